// Round 1
// baseline (1878.535 us; speedup 1.0000x reference)
//
#include <hip/hip_runtime.h>
#include <math.h>

#define B_    64
#define S_    512
#define EMB_  768
#define HID_  512
#define IMG_  2048
#define ATT_  512
#define K_    6
#define HL_   20

// ---------------------------------------------------------------------------
// mask dtype probe: int32 0/1 values have bytes at (i&3)!=0 all zero;
// a random bool (1-byte) buffer has ~75% of those nonzero.
__global__ __launch_bounds__(256)
void mask_detect(const unsigned char* __restrict__ m, int* __restrict__ flag, int nbytes) {
    __shared__ int found;
    if (threadIdx.x == 0) found = 0;
    __syncthreads();
    for (int i = threadIdx.x; i < nbytes; i += 256) {
        if ((i & 3) != 0 && m[i] != 0) found = 1;   // benign race (all write 1)
    }
    __syncthreads();
    if (threadIdx.x == 0) *flag = found;
}

// ---------------------------------------------------------------------------
// fp32 tiled GEMM: C[M,N] = act(A[M,K] @ W[K,N] + bias[N] + row_add[row/row_div, N])
// ACT: 0=none, 1=relu, 2=tanh.  Requires M%64==0, N%64==0, K%16==0.
template<int ACT>
__global__ __launch_bounds__(256)
void gemm_f32(const float* __restrict__ A, const float* __restrict__ W,
              const float* __restrict__ bias, const float* __restrict__ row_add,
              int row_div, float* __restrict__ C, int M, int N, int Kd) {
    __shared__ float As[16][68];   // [k][m], padded to break store conflicts
    __shared__ float Ws[16][64];   // [k][n]
    const int tid = threadIdx.x;
    const int bm = blockIdx.y * 64, bn = blockIdx.x * 64;
    const int tx = tid & 15, ty = tid >> 4;
    const int arow = tid >> 2, akq = tid & 3;    // A-tile load: 64 rows x 4 float4
    const int wk = tid >> 4, wnq = tid & 15;     // W-tile load: 16 rows x 16 float4

    float acc[4][4] = {};

    for (int k0 = 0; k0 < Kd; k0 += 16) {
        float4 av = *(const float4*)&A[(size_t)(bm + arow) * Kd + k0 + akq * 4];
        float4 wv = *(const float4*)&W[(size_t)(k0 + wk) * N + bn + wnq * 4];
        As[akq * 4 + 0][arow] = av.x;
        As[akq * 4 + 1][arow] = av.y;
        As[akq * 4 + 2][arow] = av.z;
        As[akq * 4 + 3][arow] = av.w;
        *(float4*)&Ws[wk][wnq * 4] = wv;
        __syncthreads();
        #pragma unroll
        for (int kk = 0; kk < 16; ++kk) {
            float4 a4 = *(const float4*)&As[kk][ty * 4];
            float4 b4 = *(const float4*)&Ws[kk][tx * 4];
            float a_[4] = {a4.x, a4.y, a4.z, a4.w};
            float b_[4] = {b4.x, b4.y, b4.z, b4.w};
            #pragma unroll
            for (int i = 0; i < 4; ++i)
                #pragma unroll
                for (int j = 0; j < 4; ++j)
                    acc[i][j] += a_[i] * b_[j];
        }
        __syncthreads();
    }

    #pragma unroll
    for (int i = 0; i < 4; ++i) {
        int row = bm + ty * 4 + i;
        float4 v;
        float* vp = &v.x;
        #pragma unroll
        for (int j = 0; j < 4; ++j) {
            int col = bn + tx * 4 + j;
            float x = acc[i][j];
            if (bias) x += bias[col];
            if (row_add) x += row_add[(size_t)(row / row_div) * N + col];
            if (ACT == 1) x = fmaxf(x, 0.f);
            if (ACT == 2) x = tanhf(x);
            vp[j] = x;
        }
        *(float4*)&C[(size_t)row * N + bn + tx * 4] = v;
    }
}

// ---------------------------------------------------------------------------
// scores[row] = t[row,:] . W_a2 + b_a2   (one wave per row)
__global__ __launch_bounds__(256)
void score_dot(const float* __restrict__ t, const float* __restrict__ W_a2,
               const float* __restrict__ b_a2, float* __restrict__ scores) {
    int row = blockIdx.x * 4 + (threadIdx.x >> 6);
    int lane = threadIdx.x & 63;
    const float* tr = t + (size_t)row * ATT_;
    float s = 0.f;
    #pragma unroll
    for (int i = 0; i < ATT_ / 64; ++i) s += tr[lane + i * 64] * W_a2[lane + i * 64];
    #pragma unroll
    for (int off = 32; off; off >>= 1) s += __shfl_down(s, off, 64);
    if (lane == 0) scores[row] = s + b_a2[0];
}

// ---------------------------------------------------------------------------
// masked softmax over S per batch, in place.
__global__ __launch_bounds__(256)
void softmax_mask(float* __restrict__ scores, const void* __restrict__ masks_raw,
                  const int* __restrict__ flag) {
    int b = blockIdx.x, tid = threadIdx.x;
    bool isb = (*flag) != 0;
    const unsigned char* mb = (const unsigned char*)masks_raw;
    const int* mi = (const int*)masks_raw;
    int lane = tid & 63, wv = tid >> 6;
    __shared__ float red[4], red2[4];

    float m = -INFINITY;
    for (int s = tid; s < S_; s += 256) {
        int idx = b * S_ + s;
        bool mk = isb ? (mb[idx] != 0) : (mi[idx] != 0);
        float v = mk ? -INFINITY : scores[idx];
        scores[idx] = v;
        m = fmaxf(m, v);
    }
    #pragma unroll
    for (int off = 32; off; off >>= 1) m = fmaxf(m, __shfl_down(m, off, 64));
    if (lane == 0) red[wv] = m;
    __syncthreads();
    if (tid == 0) red[0] = fmaxf(fmaxf(red[0], red[1]), fmaxf(red[2], red[3]));
    __syncthreads();
    float Mx = red[0];

    float sum = 0.f;
    for (int s = tid; s < S_; s += 256) {
        int idx = b * S_ + s;
        float e = expf(scores[idx] - Mx);   // expf(-inf - finite) = 0
        scores[idx] = e;
        sum += e;
    }
    #pragma unroll
    for (int off = 32; off; off >>= 1) sum += __shfl_down(sum, off, 64);
    if (lane == 0) red2[wv] = sum;
    __syncthreads();
    if (tid == 0) red2[0] = red2[0] + red2[1] + red2[2] + red2[3];
    __syncthreads();
    float inv = 1.f / red2[0];
    for (int s = tid; s < S_; s += 256) scores[b * S_ + s] *= inv;
}

// ---------------------------------------------------------------------------
// attended[b,h] = sum_s mm[b,s,h] * att_w[b,s]
__global__ __launch_bounds__(256)
void attended_k(const float* __restrict__ mm, const float* __restrict__ att_w,
                float* __restrict__ attended) {
    int b = blockIdx.x;
    int h = blockIdx.y * 256 + threadIdx.x;
    __shared__ float w[S_];
    for (int s = threadIdx.x; s < S_; s += 256) w[s] = att_w[b * S_ + s];
    __syncthreads();
    float acc = 0.f;
    for (int s = 0; s < S_; ++s)
        acc += mm[((size_t)b * S_ + s) * HID_ + h] * w[s];
    attended[b * HID_ + h] = acc;
}

// ---------------------------------------------------------------------------
// havg[bk,e] = sum_{l<cnt} prev_hist[bk,l,e] / max(cnt,1)
__global__ __launch_bounds__(256)
void hist_avg(const float* __restrict__ ph, const int* __restrict__ hcnt,
              float* __restrict__ havg) {
    int bk = blockIdx.x;
    int cnt = hcnt[bk];
    float denom = (float)(cnt > 1 ? cnt : 1);
    const float* base = ph + (size_t)bk * HL_ * EMB_;
    for (int e = threadIdx.x; e < EMB_; e += 256) {
        float s = 0.f;
        for (int l = 0; l < cnt; ++l) s += base[l * EMB_ + e];
        havg[bk * EMB_ + e] = s / denom;
    }
}

// ---------------------------------------------------------------------------
// sep = relu(sep0 + (cnt>0 ? hproj : 0)); out[bk] = (sep . attended_b) / max(||sep||,1e-12)
__global__ __launch_bounds__(256)
void combine(const float* __restrict__ sep0, const float* __restrict__ hproj,
             const int* __restrict__ hcnt, const float* __restrict__ attended,
             float* __restrict__ out) {
    int bk = blockIdx.x, tid = threadIdx.x;
    int b = bk / K_;
    int cnt = hcnt[bk];
    float sq = 0.f, dt = 0.f;
    #pragma unroll
    for (int i = 0; i < HID_ / 256; ++i) {
        int h = tid + i * 256;
        float v = sep0[bk * HID_ + h];
        if (cnt > 0) v += hproj[bk * HID_ + h];
        v = fmaxf(v, 0.f);
        sq += v * v;
        dt += v * attended[b * HID_ + h];
    }
    #pragma unroll
    for (int off = 32; off; off >>= 1) {
        sq += __shfl_down(sq, off, 64);
        dt += __shfl_down(dt, off, 64);
    }
    __shared__ float rs[4], rd[4];
    int lane = tid & 63, wv = tid >> 6;
    if (lane == 0) { rs[wv] = sq; rd[wv] = dt; }
    __syncthreads();
    if (tid == 0) {
        float Sq = rs[0] + rs[1] + rs[2] + rs[3];
        float Dt = rd[0] + rd[1] + rd[2] + rd[3];
        float norm = fmaxf(sqrtf(Sq), 1e-12f);
        out[bk] = Dt / norm;
    }
}

// ---------------------------------------------------------------------------
extern "C" void kernel_launch(void* const* d_in, const int* in_sizes, int n_in,
                              void* d_out, int out_size, void* d_ws, size_t ws_size,
                              hipStream_t stream) {
    const float* reps     = (const float*)d_in[0];
    const float* sep_imgs = (const float*)d_in[2];
    const float* vctx     = (const float*)d_in[3];
    const float* phist    = (const float*)d_in[4];
    const int*   hcnt     = (const int*)d_in[5];
    const void*  masks    = d_in[6];
    const float* W_sep = (const float*)d_in[7];
    const float* b_sep = (const float*)d_in[8];
    const float* W_e2h = (const float*)d_in[9];
    const float* b_e2h = (const float*)d_in[10];
    const float* W_hist = (const float*)d_in[11];
    const float* b_hist = (const float*)d_in[12];
    const float* W_ctx = (const float*)d_in[13];
    const float* b_ctx = (const float*)d_in[14];
    const float* W_mm = (const float*)d_in[15];
    const float* b_mm = (const float*)d_in[16];
    const float* W_a1 = (const float*)d_in[17];
    const float* b_a1 = (const float*)d_in[18];
    const float* W_a2 = (const float*)d_in[19];
    const float* b_a2 = (const float*)d_in[20];
    float* out = (float*)d_out;

    const size_t MS = (size_t)B_ * S_;          // 32768
    float* fws   = (float*)d_ws;
    float* buf0  = fws;                          // input_reps, later t   [MS*HID]
    float* buf1  = buf0 + MS * HID_;             // mm                    [MS*HID]
    float* ctx   = buf1 + MS * HID_;             // [B,HID]
    float* ctx2  = ctx + B_ * HID_;              // [B,HID]
    float* scores = ctx2 + B_ * HID_;            // [B,S] -> att_w in place
    float* attended = scores + MS;               // [B,HID]
    float* sep0  = attended + B_ * HID_;         // [B*K,HID]
    float* havg  = sep0 + B_ * K_ * HID_;        // [B*K,EMB]
    float* hproj = havg + B_ * K_ * EMB_;        // [B*K,HID]
    int*   flag  = (int*)(hproj + B_ * K_ * HID_);

    // 0. mask dtype probe
    mask_detect<<<1, 256, 0, stream>>>((const unsigned char*)masks, flag, 8192);

    // 1. ctx = relu(visual_context @ W_ctx + b_ctx)          [64,512]
    gemm_f32<1><<<dim3(8, 1), 256, 0, stream>>>(vctx, W_ctx, b_ctx, nullptr, 1,
                                                ctx, B_, HID_, K_ * IMG_);
    // 2. ctx2 = ctx @ W_mm[H:,:] + b_mm                      [64,512]
    gemm_f32<0><<<dim3(8, 1), 256, 0, stream>>>(ctx, W_mm + (size_t)HID_ * HID_, b_mm,
                                                nullptr, 1, ctx2, B_, HID_, HID_);
    // 3. input_reps = relu(reps @ W_e2h + b_e2h)             [32768,512]
    gemm_f32<1><<<dim3(8, 512), 256, 0, stream>>>(reps, W_e2h, b_e2h, nullptr, 1,
                                                  buf0, (int)MS, HID_, EMB_);
    // 4. mm = relu(input_reps @ W_mm[:H,:] + ctx2[b])        [32768,512]
    gemm_f32<1><<<dim3(8, 512), 256, 0, stream>>>(buf0, W_mm, nullptr, ctx2, S_,
                                                  buf1, (int)MS, HID_, HID_);
    // 5. t = tanh(mm @ W_a1 + b_a1)  (overwrites buf0)       [32768,512]
    gemm_f32<2><<<dim3(8, 512), 256, 0, stream>>>(buf1, W_a1, b_a1, nullptr, 1,
                                                  buf0, (int)MS, ATT_, HID_);
    // 6. scores = t . W_a2 + b_a2                            [32768]
    score_dot<<<8192, 256, 0, stream>>>(buf0, W_a2, b_a2, scores);
    // 7. masked softmax over S (in place -> att_w)
    softmax_mask<<<B_, 256, 0, stream>>>(scores, masks, flag);
    // 8. attended[b,h] = sum_s mm * att_w                    [64,512]
    attended_k<<<dim3(B_, HID_ / 256), 256, 0, stream>>>(buf1, scores, attended);
    // 9. havg                                                 [384,768]
    hist_avg<<<B_ * K_, 256, 0, stream>>>(phist, hcnt, havg);
    // 10. hproj = relu(havg @ W_hist + b_hist)                [384,512]
    gemm_f32<1><<<dim3(8, 6), 256, 0, stream>>>(havg, W_hist, b_hist, nullptr, 1,
                                                hproj, B_ * K_, HID_, EMB_);
    // 11. sep0 = separate_images @ W_sep + b_sep              [384,512]
    gemm_f32<0><<<dim3(8, 6), 256, 0, stream>>>(sep_imgs, W_sep, b_sep, nullptr, 1,
                                                sep0, B_ * K_, HID_, IMG_);
    // 12. combine: relu, L2-normalize, dot with attended -> out [384]
    combine<<<B_ * K_, 256, 0, stream>>>(sep0, hproj, hcnt, attended, out);
}

// Round 2
// 943.039 us; speedup vs baseline: 1.9920x; 1.9920x over previous
//
#include <hip/hip_runtime.h>
#include <math.h>

#define B_    64
#define S_    512
#define EMB_  768
#define HID_  512
#define IMG_  2048
#define ATT_  512
#define K_    6
#define HL_   20

// ---------------------------------------------------------------------------
// mask dtype probe: int32 0/1 values have bytes at (i&3)!=0 all zero;
// a random bool (1-byte) buffer has ~75% of those nonzero.
__global__ __launch_bounds__(256)
void mask_detect(const unsigned char* __restrict__ m, int* __restrict__ flag, int nbytes) {
    __shared__ int found;
    if (threadIdx.x == 0) found = 0;
    __syncthreads();
    for (int i = threadIdx.x; i < nbytes; i += 256) {
        if ((i & 3) != 0 && m[i] != 0) found = 1;   // benign race (all write 1)
    }
    __syncthreads();
    if (threadIdx.x == 0) *flag = found;
}

// ---------------------------------------------------------------------------
// fp32 tiled GEMM: C[M,N] = act(A[M,K] @ W[K,N] + bias[N] + row_add[row/row_div, N])
// ACT: 0=none, 1=relu, 2=tanh.  Requires M%64==0, N%64==0, K%16==0.
template<int ACT>
__global__ __launch_bounds__(256)
void gemm_f32(const float* __restrict__ A, const float* __restrict__ W,
              const float* __restrict__ bias, const float* __restrict__ row_add,
              int row_div, float* __restrict__ C, int M, int N, int Kd) {
    __shared__ float As[16][68];   // [k][m], padded to break store conflicts
    __shared__ float Ws[16][64];   // [k][n]
    const int tid = threadIdx.x;
    const int bm = blockIdx.y * 64, bn = blockIdx.x * 64;
    const int tx = tid & 15, ty = tid >> 4;
    const int arow = tid >> 2, akq = tid & 3;    // A-tile load: 64 rows x 4 float4
    const int wk = tid >> 4, wnq = tid & 15;     // W-tile load: 16 rows x 16 float4

    float acc[4][4] = {};

    for (int k0 = 0; k0 < Kd; k0 += 16) {
        float4 av = *(const float4*)&A[(size_t)(bm + arow) * Kd + k0 + akq * 4];
        float4 wv = *(const float4*)&W[(size_t)(k0 + wk) * N + bn + wnq * 4];
        As[akq * 4 + 0][arow] = av.x;
        As[akq * 4 + 1][arow] = av.y;
        As[akq * 4 + 2][arow] = av.z;
        As[akq * 4 + 3][arow] = av.w;
        *(float4*)&Ws[wk][wnq * 4] = wv;
        __syncthreads();
        #pragma unroll
        for (int kk = 0; kk < 16; ++kk) {
            float4 a4 = *(const float4*)&As[kk][ty * 4];
            float4 b4 = *(const float4*)&Ws[kk][tx * 4];
            float a_[4] = {a4.x, a4.y, a4.z, a4.w};
            float b_[4] = {b4.x, b4.y, b4.z, b4.w};
            #pragma unroll
            for (int i = 0; i < 4; ++i)
                #pragma unroll
                for (int j = 0; j < 4; ++j)
                    acc[i][j] += a_[i] * b_[j];
        }
        __syncthreads();
    }

    #pragma unroll
    for (int i = 0; i < 4; ++i) {
        int row = bm + ty * 4 + i;
        float4 v;
        float* vp = &v.x;
        #pragma unroll
        for (int j = 0; j < 4; ++j) {
            int col = bn + tx * 4 + j;
            float x = acc[i][j];
            if (bias) x += bias[col];
            if (row_add) x += row_add[(size_t)(row / row_div) * N + col];
            if (ACT == 1) x = fmaxf(x, 0.f);
            if (ACT == 2) x = tanhf(x);
            vp[j] = x;
        }
        *(float4*)&C[(size_t)row * N + bn + tx * 4] = v;
    }
}

// ---------------------------------------------------------------------------
// split-K partial GEMM: P[z, m, n] = A[m, kz..kz+kps) @ W[.., n]
// Same tile structure as gemm_f32; no bias/act. kps % 16 == 0.
__global__ __launch_bounds__(256)
void gemm_splitk(const float* __restrict__ A, const float* __restrict__ W,
                 float* __restrict__ P, int M, int N, int Kd, int kps) {
    __shared__ float As[16][68];
    __shared__ float Ws[16][64];
    const int tid = threadIdx.x;
    const int bm = blockIdx.y * 64, bn = blockIdx.x * 64;
    const int ks = blockIdx.z;
    const int tx = tid & 15, ty = tid >> 4;
    const int arow = tid >> 2, akq = tid & 3;
    const int wk = tid >> 4, wnq = tid & 15;

    float acc[4][4] = {};
    const int kbeg = ks * kps, kend = kbeg + kps;

    for (int k0 = kbeg; k0 < kend; k0 += 16) {
        float4 av = *(const float4*)&A[(size_t)(bm + arow) * Kd + k0 + akq * 4];
        float4 wv = *(const float4*)&W[(size_t)(k0 + wk) * N + bn + wnq * 4];
        As[akq * 4 + 0][arow] = av.x;
        As[akq * 4 + 1][arow] = av.y;
        As[akq * 4 + 2][arow] = av.z;
        As[akq * 4 + 3][arow] = av.w;
        *(float4*)&Ws[wk][wnq * 4] = wv;
        __syncthreads();
        #pragma unroll
        for (int kk = 0; kk < 16; ++kk) {
            float4 a4 = *(const float4*)&As[kk][ty * 4];
            float4 b4 = *(const float4*)&Ws[kk][tx * 4];
            float a_[4] = {a4.x, a4.y, a4.z, a4.w};
            float b_[4] = {b4.x, b4.y, b4.z, b4.w};
            #pragma unroll
            for (int i = 0; i < 4; ++i)
                #pragma unroll
                for (int j = 0; j < 4; ++j)
                    acc[i][j] += a_[i] * b_[j];
        }
        __syncthreads();
    }

    float* Pbase = P + (size_t)ks * M * N;
    #pragma unroll
    for (int i = 0; i < 4; ++i) {
        int row = bm + ty * 4 + i;
        float4 v = {acc[i][0], acc[i][1], acc[i][2], acc[i][3]};
        *(float4*)&Pbase[(size_t)row * N + bn + tx * 4] = v;
    }
}

// ---------------------------------------------------------------------------
// reduce split-K partials: C[idx] = act(sum_z P[z,idx] + bias[idx % N])
template<int ACT>
__global__ __launch_bounds__(256)
void reduce_k(const float* __restrict__ P, const float* __restrict__ bias,
              float* __restrict__ C, int MN, int N, int nsplit) {
    int idx = blockIdx.x * 256 + threadIdx.x;
    if (idx >= MN) return;
    float s = 0.f;
    for (int z = 0; z < nsplit; ++z) s += P[(size_t)z * MN + idx];
    if (bias) s += bias[idx & (N - 1)];
    if (ACT == 1) s = fmaxf(s, 0.f);
    C[idx] = s;
}

// ---------------------------------------------------------------------------
// scores[row] = t[row,:] . W_a2 + b_a2   (one wave per row)
__global__ __launch_bounds__(256)
void score_dot(const float* __restrict__ t, const float* __restrict__ W_a2,
               const float* __restrict__ b_a2, float* __restrict__ scores) {
    int row = blockIdx.x * 4 + (threadIdx.x >> 6);
    int lane = threadIdx.x & 63;
    const float* tr = t + (size_t)row * ATT_;
    float s = 0.f;
    #pragma unroll
    for (int i = 0; i < ATT_ / 64; ++i) s += tr[lane + i * 64] * W_a2[lane + i * 64];
    #pragma unroll
    for (int off = 32; off; off >>= 1) s += __shfl_down(s, off, 64);
    if (lane == 0) scores[row] = s + b_a2[0];
}

// ---------------------------------------------------------------------------
// masked softmax over S per batch, in place.
__global__ __launch_bounds__(256)
void softmax_mask(float* __restrict__ scores, const void* __restrict__ masks_raw,
                  const int* __restrict__ flag) {
    int b = blockIdx.x, tid = threadIdx.x;
    bool isb = (*flag) != 0;
    const unsigned char* mb = (const unsigned char*)masks_raw;
    const int* mi = (const int*)masks_raw;
    int lane = tid & 63, wv = tid >> 6;
    __shared__ float red[4], red2[4];

    float m = -INFINITY;
    for (int s = tid; s < S_; s += 256) {
        int idx = b * S_ + s;
        bool mk = isb ? (mb[idx] != 0) : (mi[idx] != 0);
        float v = mk ? -INFINITY : scores[idx];
        scores[idx] = v;
        m = fmaxf(m, v);
    }
    #pragma unroll
    for (int off = 32; off; off >>= 1) m = fmaxf(m, __shfl_down(m, off, 64));
    if (lane == 0) red[wv] = m;
    __syncthreads();
    if (tid == 0) red[0] = fmaxf(fmaxf(red[0], red[1]), fmaxf(red[2], red[3]));
    __syncthreads();
    float Mx = red[0];

    float sum = 0.f;
    for (int s = tid; s < S_; s += 256) {
        int idx = b * S_ + s;
        float e = expf(scores[idx] - Mx);   // expf(-inf - finite) = 0
        scores[idx] = e;
        sum += e;
    }
    #pragma unroll
    for (int off = 32; off; off >>= 1) sum += __shfl_down(sum, off, 64);
    if (lane == 0) red2[wv] = sum;
    __syncthreads();
    if (tid == 0) red2[0] = red2[0] + red2[1] + red2[2] + red2[3];
    __syncthreads();
    float inv = 1.f / red2[0];
    for (int s = tid; s < S_; s += 256) scores[b * S_ + s] *= inv;
}

// ---------------------------------------------------------------------------
// attended[b,h] = sum_s mm[b,s,h] * att_w[b,s]
__global__ __launch_bounds__(256)
void attended_k(const float* __restrict__ mm, const float* __restrict__ att_w,
                float* __restrict__ attended) {
    int b = blockIdx.x;
    int h = blockIdx.y * 256 + threadIdx.x;
    __shared__ float w[S_];
    for (int s = threadIdx.x; s < S_; s += 256) w[s] = att_w[b * S_ + s];
    __syncthreads();
    float acc = 0.f;
    for (int s = 0; s < S_; ++s)
        acc += mm[((size_t)b * S_ + s) * HID_ + h] * w[s];
    attended[b * HID_ + h] = acc;
}

// ---------------------------------------------------------------------------
// havg[bk,e] = sum_{l<cnt} prev_hist[bk,l,e] / max(cnt,1)
__global__ __launch_bounds__(256)
void hist_avg(const float* __restrict__ ph, const int* __restrict__ hcnt,
              float* __restrict__ havg) {
    int bk = blockIdx.x;
    int cnt = hcnt[bk];
    float denom = (float)(cnt > 1 ? cnt : 1);
    const float* base = ph + (size_t)bk * HL_ * EMB_;
    for (int e = threadIdx.x; e < EMB_; e += 256) {
        float s = 0.f;
        for (int l = 0; l < cnt; ++l) s += base[l * EMB_ + e];
        havg[bk * EMB_ + e] = s / denom;
    }
}

// ---------------------------------------------------------------------------
// sep = relu(sep0 + (cnt>0 ? hproj : 0)); out[bk] = (sep . attended_b) / max(||sep||,1e-12)
__global__ __launch_bounds__(256)
void combine(const float* __restrict__ sep0, const float* __restrict__ hproj,
             const int* __restrict__ hcnt, const float* __restrict__ attended,
             float* __restrict__ out) {
    int bk = blockIdx.x, tid = threadIdx.x;
    int b = bk / K_;
    int cnt = hcnt[bk];
    float sq = 0.f, dt = 0.f;
    #pragma unroll
    for (int i = 0; i < HID_ / 256; ++i) {
        int h = tid + i * 256;
        float v = sep0[bk * HID_ + h];
        if (cnt > 0) v += hproj[bk * HID_ + h];
        v = fmaxf(v, 0.f);
        sq += v * v;
        dt += v * attended[b * HID_ + h];
    }
    #pragma unroll
    for (int off = 32; off; off >>= 1) {
        sq += __shfl_down(sq, off, 64);
        dt += __shfl_down(dt, off, 64);
    }
    __shared__ float rs[4], rd[4];
    int lane = tid & 63, wv = tid >> 6;
    if (lane == 0) { rs[wv] = sq; rd[wv] = dt; }
    __syncthreads();
    if (tid == 0) {
        float Sq = rs[0] + rs[1] + rs[2] + rs[3];
        float Dt = rd[0] + rd[1] + rd[2] + rd[3];
        float norm = fmaxf(sqrtf(Sq), 1e-12f);
        out[bk] = Dt / norm;
    }
}

// ---------------------------------------------------------------------------
extern "C" void kernel_launch(void* const* d_in, const int* in_sizes, int n_in,
                              void* d_out, int out_size, void* d_ws, size_t ws_size,
                              hipStream_t stream) {
    const float* reps     = (const float*)d_in[0];
    const float* sep_imgs = (const float*)d_in[2];
    const float* vctx     = (const float*)d_in[3];
    const float* phist    = (const float*)d_in[4];
    const int*   hcnt     = (const int*)d_in[5];
    const void*  masks    = d_in[6];
    const float* W_sep = (const float*)d_in[7];
    const float* b_sep = (const float*)d_in[8];
    const float* W_e2h = (const float*)d_in[9];
    const float* b_e2h = (const float*)d_in[10];
    const float* W_hist = (const float*)d_in[11];
    const float* b_hist = (const float*)d_in[12];
    const float* W_ctx = (const float*)d_in[13];
    const float* b_ctx = (const float*)d_in[14];
    const float* W_mm = (const float*)d_in[15];
    const float* b_mm = (const float*)d_in[16];
    const float* W_a1 = (const float*)d_in[17];
    const float* b_a1 = (const float*)d_in[18];
    const float* W_a2 = (const float*)d_in[19];
    const float* b_a2 = (const float*)d_in[20];
    float* out = (float*)d_out;

    const size_t MS = (size_t)B_ * S_;          // 32768
    float* fws   = (float*)d_ws;
    float* buf0  = fws;                          // input_reps, later t   [MS*HID]
    float* buf1  = buf0 + MS * HID_;             // mm; also split-K partial scratch
    float* ctx   = buf1 + MS * HID_;             // [B,HID]
    float* ctx2  = ctx + B_ * HID_;              // [B,HID]
    float* scores = ctx2 + B_ * HID_;            // [B,S] -> att_w in place
    float* attended = scores + MS;               // [B,HID]
    float* sep0  = attended + B_ * HID_;         // [B*K,HID]
    float* havg  = sep0 + B_ * K_ * HID_;        // [B*K,EMB]
    float* hproj = havg + B_ * K_ * EMB_;        // [B*K,HID]
    int*   flag  = (int*)(hproj + B_ * K_ * HID_);

    // 0. mask dtype probe
    mask_detect<<<1, 256, 0, stream>>>((const unsigned char*)masks, flag, 8192);

    // 1. ctx = relu(visual_context @ W_ctx + b_ctx)   [64,512], K=12288, split-K 64
    {
        const int nsp = 64, kps = (K_ * IMG_) / nsp;   // 192
        gemm_splitk<<<dim3(8, 1, nsp), 256, 0, stream>>>(vctx, W_ctx, buf1,
                                                         B_, HID_, K_ * IMG_, kps);
        reduce_k<1><<<(B_ * HID_ + 255) / 256, 256, 0, stream>>>(buf1, b_ctx, ctx,
                                                                 B_ * HID_, HID_, nsp);
    }
    // 2. ctx2 = ctx @ W_mm[H:,:] + b_mm               [64,512], K=512, split-K 8
    {
        const int nsp = 8, kps = HID_ / nsp;           // 64
        gemm_splitk<<<dim3(8, 1, nsp), 256, 0, stream>>>(ctx, W_mm + (size_t)HID_ * HID_,
                                                         buf1, B_, HID_, HID_, kps);
        reduce_k<0><<<(B_ * HID_ + 255) / 256, 256, 0, stream>>>(buf1, b_mm, ctx2,
                                                                 B_ * HID_, HID_, nsp);
    }
    // 3. input_reps = relu(reps @ W_e2h + b_e2h)      [32768,512]
    gemm_f32<1><<<dim3(8, 512), 256, 0, stream>>>(reps, W_e2h, b_e2h, nullptr, 1,
                                                  buf0, (int)MS, HID_, EMB_);
    // 4. mm = relu(input_reps @ W_mm[:H,:] + ctx2[b]) [32768,512]
    gemm_f32<1><<<dim3(8, 512), 256, 0, stream>>>(buf0, W_mm, nullptr, ctx2, S_,
                                                  buf1, (int)MS, HID_, HID_);
    // 5. t = tanh(mm @ W_a1 + b_a1)  (overwrites buf0)
    gemm_f32<2><<<dim3(8, 512), 256, 0, stream>>>(buf1, W_a1, b_a1, nullptr, 1,
                                                  buf0, (int)MS, ATT_, HID_);
    // 6. scores = t . W_a2 + b_a2
    score_dot<<<8192, 256, 0, stream>>>(buf0, W_a2, b_a2, scores);
    // 7. masked softmax over S (in place -> att_w)
    softmax_mask<<<B_, 256, 0, stream>>>(scores, masks, flag);
    // 8. attended[b,h] = sum_s mm * att_w             [64,512]
    attended_k<<<dim3(B_, HID_ / 256), 256, 0, stream>>>(buf1, scores, attended);
    // 9. havg                                          [384,768]
    hist_avg<<<B_ * K_, 256, 0, stream>>>(phist, hcnt, havg);
    // 10. hproj = relu(havg @ W_hist + b_hist)         [384,512], K=768, split-K 8
    {
        const int nsp = 8, kps = EMB_ / nsp;           // 96
        gemm_splitk<<<dim3(8, 6, nsp), 256, 0, stream>>>(havg, W_hist, buf1,
                                                         B_ * K_, HID_, EMB_, kps);
        reduce_k<1><<<(B_ * K_ * HID_ + 255) / 256, 256, 0, stream>>>(buf1, b_hist, hproj,
                                                                      B_ * K_ * HID_, HID_, nsp);
    }
    // 11. sep0 = separate_images @ W_sep + b_sep       [384,512], K=2048, split-K 16
    {
        const int nsp = 16, kps = IMG_ / nsp;          // 128
        gemm_splitk<<<dim3(8, 6, nsp), 256, 0, stream>>>(sep_imgs, W_sep, buf1,
                                                         B_ * K_, HID_, IMG_, kps);
        reduce_k<0><<<(B_ * K_ * HID_ + 255) / 256, 256, 0, stream>>>(buf1, b_sep, sep0,
                                                                      B_ * K_ * HID_, HID_, nsp);
    }
    // 12. combine: relu, L2-normalize, dot with attended -> out [384]
    combine<<<B_ * K_, 256, 0, stream>>>(sep0, hproj, hcnt, attended, out);
}

// Round 3
// 343.723 us; speedup vs baseline: 5.4653x; 2.7436x over previous
//
#include <hip/hip_runtime.h>
#include <math.h>

#define B_    64
#define S_    512
#define EMB_  768
#define HID_  512
#define IMG_  2048
#define ATT_  512
#define K_    6
#define HL_   20

typedef __attribute__((ext_vector_type(8))) short bf16x8;
typedef __attribute__((ext_vector_type(4))) float f32x4;

__device__ __forceinline__ unsigned short f2b(float f) {
    unsigned int u = __float_as_uint(f);
    u += 0x7fffu + ((u >> 16) & 1u);          // RNE
    return (unsigned short)(u >> 16);
}
__device__ __forceinline__ float b2f(unsigned short s) {
    return __uint_as_float(((unsigned int)s) << 16);
}

#define GLD_LDS16(gp, lp)                                                        \
    __builtin_amdgcn_global_load_lds(                                            \
        (const __attribute__((address_space(1))) void*)(gp),                     \
        (__attribute__((address_space(3))) void*)(lp), 16, 0, 0)

// ---------------------------------------------------------------------------
// mask dtype probe: int32 0/1 values have bytes at (i&3)!=0 all zero.
__global__ __launch_bounds__(256)
void mask_detect(const unsigned char* __restrict__ m, int* __restrict__ flag, int nbytes) {
    __shared__ int found;
    if (threadIdx.x == 0) found = 0;
    __syncthreads();
    for (int i = threadIdx.x; i < nbytes; i += 256) {
        if ((i & 3) != 0 && m[i] != 0) found = 1;
    }
    __syncthreads();
    if (threadIdx.x == 0) *flag = found;
}

// ---------------------------------------------------------------------------
// fp32 -> bf16 bulk convert, 8 elems/thread/iter
__global__ __launch_bounds__(256)
void cvt_f32_bf16(const float* __restrict__ in, unsigned short* __restrict__ out, int n8) {
    int stride = gridDim.x * 256;
    for (int i = blockIdx.x * 256 + threadIdx.x; i < n8; i += stride) {
        float4 a = ((const float4*)in)[i * 2];
        float4 b = ((const float4*)in)[i * 2 + 1];
        unsigned short r[8] = {f2b(a.x), f2b(a.y), f2b(a.z), f2b(a.w),
                               f2b(b.x), f2b(b.y), f2b(b.z), f2b(b.w)};
        ((uint4*)out)[i] = *(uint4*)r;
    }
}

// ---------------------------------------------------------------------------
// Wt[n][k] = bf16(W[k][n]).  grid (Kd/32, N/32), block 256.
__global__ __launch_bounds__(256)
void transpose_cvt(const float* __restrict__ W, unsigned short* __restrict__ Wt,
                   int Kd, int N) {
    __shared__ float tile[32][33];
    int k0 = blockIdx.x * 32, n0 = blockIdx.y * 32;
    int tx = threadIdx.x & 31, ty = threadIdx.x >> 5;   // 32 x 8
    #pragma unroll
    for (int i = 0; i < 4; ++i)
        tile[ty + i * 8][tx] = W[(size_t)(k0 + ty + i * 8) * N + n0 + tx];
    __syncthreads();
    #pragma unroll
    for (int i = 0; i < 4; ++i)
        Wt[(size_t)(n0 + ty + i * 8) * Kd + k0 + tx] = f2b(tile[tx][ty + i * 8]);
}

// ---------------------------------------------------------------------------
// bf16 MFMA GEMM (m97 structure): C = act(A[M,K] @ Bt[N,K]^T + bias + row_add)
// 128x128 tile, BK=32, 4 waves (2x2), 4x4 16x16x32 fragments per wave.
// ACT: 0=none, 1=relu, 2=tanh.  M%128==0, N%128==0, Kd%32==0. Output bf16.
template<int ACT>
__global__ __launch_bounds__(256)
void gemm_bf16(const unsigned short* __restrict__ A, const unsigned short* __restrict__ Bt,
               const float* __restrict__ bias, const float* __restrict__ row_add,
               int row_div, unsigned short* __restrict__ Co, int M, int N, int Kd) {
    __shared__ unsigned short Als[128 * 32];
    __shared__ unsigned short Bls[128 * 32];
    const int tid = threadIdx.x;
    const int bm = blockIdx.y * 128, bn = blockIdx.x * 128;
    const int lane = tid & 63;
    const int wid = tid >> 6;
    const int wr = wid >> 1, wc = wid & 1;

    f32x4 acc[4][4] = {};

    const int c0 = tid, c1 = 256 + tid;
    const int r0 = c0 >> 2, kc0 = c0 & 3;   // chunk -> (row, k-chunk)
    const int r1 = c1 >> 2, kc1 = c1 & 3;
    const int fr = lane & 15, fk = (lane >> 4) * 8;

    for (int k0 = 0; k0 < Kd; k0 += 32) {
        GLD_LDS16(A + (size_t)(bm + r0) * Kd + k0 + kc0 * 8, Als + c0 * 8);
        GLD_LDS16(A + (size_t)(bm + r1) * Kd + k0 + kc1 * 8, Als + c1 * 8);
        GLD_LDS16(Bt + (size_t)(bn + r0) * Kd + k0 + kc0 * 8, Bls + c0 * 8);
        GLD_LDS16(Bt + (size_t)(bn + r1) * Kd + k0 + kc1 * 8, Bls + c1 * 8);
        __syncthreads();

        bf16x8 af[4], bf[4];
        #pragma unroll
        for (int m = 0; m < 4; ++m)
            af[m] = *(const bf16x8*)&Als[(wr * 64 + m * 16 + fr) * 32 + fk];
        #pragma unroll
        for (int n = 0; n < 4; ++n)
            bf[n] = *(const bf16x8*)&Bls[(wc * 64 + n * 16 + fr) * 32 + fk];
        #pragma unroll
        for (int m = 0; m < 4; ++m)
            #pragma unroll
            for (int n = 0; n < 4; ++n)
                acc[m][n] = __builtin_amdgcn_mfma_f32_16x16x32_bf16(af[m], bf[n], acc[m][n], 0, 0, 0);
        __syncthreads();
    }

    const int rg = lane >> 4;
    #pragma unroll
    for (int m = 0; m < 4; ++m) {
        #pragma unroll
        for (int n = 0; n < 4; ++n) {
            int col = bn + wc * 64 + n * 16 + fr;
            float badd = bias ? bias[col] : 0.f;
            #pragma unroll
            for (int r = 0; r < 4; ++r) {
                int row = bm + wr * 64 + m * 16 + rg * 4 + r;
                float x = acc[m][n][r] + badd;
                if (row_add) x += row_add[(size_t)(row / row_div) * N + col];
                if (ACT == 1) x = fmaxf(x, 0.f);
                if (ACT == 2) x = tanhf(x);
                Co[(size_t)row * N + col] = f2b(x);
            }
        }
    }
}

// ---------------------------------------------------------------------------
// split-K partial fp32 GEMM: P[z, m, n] = A[m, kz..kz+kps) @ W[.., n]
__global__ __launch_bounds__(256)
void gemm_splitk(const float* __restrict__ A, const float* __restrict__ W,
                 float* __restrict__ P, int M, int N, int Kd, int kps) {
    __shared__ float As[16][68];
    __shared__ float Ws[16][64];
    const int tid = threadIdx.x;
    const int bm = blockIdx.y * 64, bn = blockIdx.x * 64;
    const int ks = blockIdx.z;
    const int tx = tid & 15, ty = tid >> 4;
    const int arow = tid >> 2, akq = tid & 3;
    const int wk = tid >> 4, wnq = tid & 15;

    float acc[4][4] = {};
    const int kbeg = ks * kps, kend = kbeg + kps;

    for (int k0 = kbeg; k0 < kend; k0 += 16) {
        float4 av = *(const float4*)&A[(size_t)(bm + arow) * Kd + k0 + akq * 4];
        float4 wv = *(const float4*)&W[(size_t)(k0 + wk) * N + bn + wnq * 4];
        As[akq * 4 + 0][arow] = av.x;
        As[akq * 4 + 1][arow] = av.y;
        As[akq * 4 + 2][arow] = av.z;
        As[akq * 4 + 3][arow] = av.w;
        *(float4*)&Ws[wk][wnq * 4] = wv;
        __syncthreads();
        #pragma unroll
        for (int kk = 0; kk < 16; ++kk) {
            float4 a4 = *(const float4*)&As[kk][ty * 4];
            float4 b4 = *(const float4*)&Ws[kk][tx * 4];
            float a_[4] = {a4.x, a4.y, a4.z, a4.w};
            float b_[4] = {b4.x, b4.y, b4.z, b4.w};
            #pragma unroll
            for (int i = 0; i < 4; ++i)
                #pragma unroll
                for (int j = 0; j < 4; ++j)
                    acc[i][j] += a_[i] * b_[j];
        }
        __syncthreads();
    }

    float* Pbase = P + (size_t)ks * M * N;
    #pragma unroll
    for (int i = 0; i < 4; ++i) {
        int row = bm + ty * 4 + i;
        float4 v = {acc[i][0], acc[i][1], acc[i][2], acc[i][3]};
        *(float4*)&Pbase[(size_t)row * N + bn + tx * 4] = v;
    }
}

// ---------------------------------------------------------------------------
template<int ACT>
__global__ __launch_bounds__(256)
void reduce_k(const float* __restrict__ P, const float* __restrict__ bias,
              float* __restrict__ C, int MN, int N, int nsplit) {
    int idx = blockIdx.x * 256 + threadIdx.x;
    if (idx >= MN) return;
    float s = 0.f;
    for (int z = 0; z < nsplit; ++z) s += P[(size_t)z * MN + idx];
    if (bias) s += bias[idx & (N - 1)];
    if (ACT == 1) s = fmaxf(s, 0.f);
    C[idx] = s;
}

// ---------------------------------------------------------------------------
// scores[row] = bf16(t[row,:]) . W_a2 + b_a2   (one wave per row)
__global__ __launch_bounds__(256)
void score_dot(const unsigned short* __restrict__ t, const float* __restrict__ W_a2,
               const float* __restrict__ b_a2, float* __restrict__ scores) {
    int row = blockIdx.x * 4 + (threadIdx.x >> 6);
    int lane = threadIdx.x & 63;
    const unsigned short* tr = t + (size_t)row * ATT_;
    float s = 0.f;
    #pragma unroll
    for (int i = 0; i < ATT_ / 64; ++i)
        s += b2f(tr[lane + i * 64]) * W_a2[lane + i * 64];
    #pragma unroll
    for (int off = 32; off; off >>= 1) s += __shfl_down(s, off, 64);
    if (lane == 0) scores[row] = s + b_a2[0];
}

// ---------------------------------------------------------------------------
__global__ __launch_bounds__(256)
void softmax_mask(float* __restrict__ scores, const void* __restrict__ masks_raw,
                  const int* __restrict__ flag) {
    int b = blockIdx.x, tid = threadIdx.x;
    bool isb = (*flag) != 0;
    const unsigned char* mb = (const unsigned char*)masks_raw;
    const int* mi = (const int*)masks_raw;
    int lane = tid & 63, wv = tid >> 6;
    __shared__ float red[4], red2[4];

    float m = -INFINITY;
    for (int s = tid; s < S_; s += 256) {
        int idx = b * S_ + s;
        bool mk = isb ? (mb[idx] != 0) : (mi[idx] != 0);
        float v = mk ? -INFINITY : scores[idx];
        scores[idx] = v;
        m = fmaxf(m, v);
    }
    #pragma unroll
    for (int off = 32; off; off >>= 1) m = fmaxf(m, __shfl_down(m, off, 64));
    if (lane == 0) red[wv] = m;
    __syncthreads();
    if (tid == 0) red[0] = fmaxf(fmaxf(red[0], red[1]), fmaxf(red[2], red[3]));
    __syncthreads();
    float Mx = red[0];

    float sum = 0.f;
    for (int s = tid; s < S_; s += 256) {
        int idx = b * S_ + s;
        float e = expf(scores[idx] - Mx);
        scores[idx] = e;
        sum += e;
    }
    #pragma unroll
    for (int off = 32; off; off >>= 1) sum += __shfl_down(sum, off, 64);
    if (lane == 0) red2[wv] = sum;
    __syncthreads();
    if (tid == 0) red2[0] = red2[0] + red2[1] + red2[2] + red2[3];
    __syncthreads();
    float inv = 1.f / red2[0];
    for (int s = tid; s < S_; s += 256) scores[b * S_ + s] *= inv;
}

// ---------------------------------------------------------------------------
// attended[b,h] = sum_s bf16(mm[b,s,h]) * att_w[b,s]
__global__ __launch_bounds__(256)
void attended_k(const unsigned short* __restrict__ mm, const float* __restrict__ att_w,
                float* __restrict__ attended) {
    int b = blockIdx.x;
    int h = blockIdx.y * 256 + threadIdx.x;
    __shared__ float w[S_];
    for (int s = threadIdx.x; s < S_; s += 256) w[s] = att_w[b * S_ + s];
    __syncthreads();
    float acc = 0.f;
    for (int s = 0; s < S_; ++s)
        acc += b2f(mm[((size_t)b * S_ + s) * HID_ + h]) * w[s];
    attended[b * HID_ + h] = acc;
}

// ---------------------------------------------------------------------------
__global__ __launch_bounds__(256)
void hist_avg(const float* __restrict__ ph, const int* __restrict__ hcnt,
              float* __restrict__ havg) {
    int bk = blockIdx.x;
    int cnt = hcnt[bk];
    float denom = (float)(cnt > 1 ? cnt : 1);
    const float* base = ph + (size_t)bk * HL_ * EMB_;
    for (int e = threadIdx.x; e < EMB_; e += 256) {
        float s = 0.f;
        for (int l = 0; l < cnt; ++l) s += base[l * EMB_ + e];
        havg[bk * EMB_ + e] = s / denom;
    }
}

// ---------------------------------------------------------------------------
__global__ __launch_bounds__(256)
void combine(const float* __restrict__ sep0, const float* __restrict__ hproj,
             const int* __restrict__ hcnt, const float* __restrict__ attended,
             float* __restrict__ out) {
    int bk = blockIdx.x, tid = threadIdx.x;
    int b = bk / K_;
    int cnt = hcnt[bk];
    float sq = 0.f, dt = 0.f;
    #pragma unroll
    for (int i = 0; i < HID_ / 256; ++i) {
        int h = tid + i * 256;
        float v = sep0[bk * HID_ + h];
        if (cnt > 0) v += hproj[bk * HID_ + h];
        v = fmaxf(v, 0.f);
        sq += v * v;
        dt += v * attended[b * HID_ + h];
    }
    #pragma unroll
    for (int off = 32; off; off >>= 1) {
        sq += __shfl_down(sq, off, 64);
        dt += __shfl_down(dt, off, 64);
    }
    __shared__ float rs[4], rd[4];
    int lane = tid & 63, wv = tid >> 6;
    if (lane == 0) { rs[wv] = sq; rd[wv] = dt; }
    __syncthreads();
    if (tid == 0) {
        float Sq = rs[0] + rs[1] + rs[2] + rs[3];
        float Dt = rd[0] + rd[1] + rd[2] + rd[3];
        float norm = fmaxf(sqrtf(Sq), 1e-12f);
        out[bk] = Dt / norm;
    }
}

// ---------------------------------------------------------------------------
extern "C" void kernel_launch(void* const* d_in, const int* in_sizes, int n_in,
                              void* d_out, int out_size, void* d_ws, size_t ws_size,
                              hipStream_t stream) {
    const float* reps     = (const float*)d_in[0];
    const float* sep_imgs = (const float*)d_in[2];
    const float* vctx     = (const float*)d_in[3];
    const float* phist    = (const float*)d_in[4];
    const int*   hcnt     = (const int*)d_in[5];
    const void*  masks    = d_in[6];
    const float* W_sep = (const float*)d_in[7];
    const float* b_sep = (const float*)d_in[8];
    const float* W_e2h = (const float*)d_in[9];
    const float* b_e2h = (const float*)d_in[10];
    const float* W_hist = (const float*)d_in[11];
    const float* b_hist = (const float*)d_in[12];
    const float* W_ctx = (const float*)d_in[13];
    const float* b_ctx = (const float*)d_in[14];
    const float* W_mm = (const float*)d_in[15];
    const float* b_mm = (const float*)d_in[16];
    const float* W_a1 = (const float*)d_in[17];
    const float* b_a1 = (const float*)d_in[18];
    const float* W_a2 = (const float*)d_in[19];
    const float* b_a2 = (const float*)d_in[20];
    float* out = (float*)d_out;

    const size_t MS = (size_t)B_ * S_;                     // 32768

    // ---- workspace layout ----
    unsigned short* repsb = (unsigned short*)d_ws;         // [32768*768] bf16
    unsigned short* actA  = repsb + MS * EMB_;             // [32768*512] input_reps, later t
    unsigned short* actB  = actA + MS * HID_;              // [32768*512] mm
    unsigned short* WtE2H = actB + MS * HID_;              // [512*768]
    unsigned short* WtMM  = WtE2H + (size_t)EMB_ * HID_;   // [512*512]
    unsigned short* WtA1  = WtMM + (size_t)HID_ * HID_;    // [512*512]
    float* skbuf = (float*)(WtA1 + (size_t)HID_ * HID_);   // split-K scratch (<=16*384*512)
    float* ctx   = skbuf + (size_t)16 * 384 * 512;
    float* ctx2  = ctx + B_ * HID_;
    float* scores = ctx2 + B_ * HID_;                      // [B,S]
    float* attended = scores + MS;
    float* sep0  = attended + B_ * HID_;
    float* havg  = sep0 + B_ * K_ * HID_;
    float* hproj = havg + B_ * K_ * EMB_;
    int*   flag  = (int*)(hproj + B_ * K_ * HID_);

    // 0. mask dtype probe
    mask_detect<<<1, 256, 0, stream>>>((const unsigned char*)masks, flag, 8192);

    // 0b. conversions for MFMA path
    cvt_f32_bf16<<<2048, 256, 0, stream>>>(reps, repsb, (int)(MS * EMB_ / 8));
    transpose_cvt<<<dim3(EMB_ / 32, HID_ / 32), 256, 0, stream>>>(W_e2h, WtE2H, EMB_, HID_);
    transpose_cvt<<<dim3(HID_ / 32, HID_ / 32), 256, 0, stream>>>(W_mm, WtMM, HID_, HID_);
    transpose_cvt<<<dim3(HID_ / 32, HID_ / 32), 256, 0, stream>>>(W_a1, WtA1, HID_, HID_);

    // 1. ctx = relu(visual_context @ W_ctx + b_ctx)   [64,512], K=12288, split-K 64
    {
        const int nsp = 64, kps = (K_ * IMG_) / nsp;
        gemm_splitk<<<dim3(8, 1, nsp), 256, 0, stream>>>(vctx, W_ctx, skbuf,
                                                         B_, HID_, K_ * IMG_, kps);
        reduce_k<1><<<(B_ * HID_ + 255) / 256, 256, 0, stream>>>(skbuf, b_ctx, ctx,
                                                                 B_ * HID_, HID_, nsp);
    }
    // 2. ctx2 = ctx @ W_mm[H:,:] + b_mm               [64,512], K=512, split-K 8
    {
        const int nsp = 8, kps = HID_ / nsp;
        gemm_splitk<<<dim3(8, 1, nsp), 256, 0, stream>>>(ctx, W_mm + (size_t)HID_ * HID_,
                                                         skbuf, B_, HID_, HID_, kps);
        reduce_k<0><<<(B_ * HID_ + 255) / 256, 256, 0, stream>>>(skbuf, b_mm, ctx2,
                                                                 B_ * HID_, HID_, nsp);
    }
    // 3. input_reps = relu(reps @ W_e2h + b_e2h)      [32768,512] bf16 MFMA
    gemm_bf16<1><<<dim3(4, 256), 256, 0, stream>>>(repsb, WtE2H, b_e2h, nullptr, 1,
                                                   actA, (int)MS, HID_, EMB_);
    // 4. mm = relu(input_reps @ W_mm[:H,:] + ctx2[b]) [32768,512] bf16 MFMA
    gemm_bf16<1><<<dim3(4, 256), 256, 0, stream>>>(actA, WtMM, nullptr, ctx2, S_,
                                                   actB, (int)MS, HID_, HID_);
    // 5. t = tanh(mm @ W_a1 + b_a1)  (reuses actA)    [32768,512] bf16 MFMA
    gemm_bf16<2><<<dim3(4, 256), 256, 0, stream>>>(actB, WtA1, b_a1, nullptr, 1,
                                                   actA, (int)MS, ATT_, HID_);
    // 6. scores = t . W_a2 + b_a2
    score_dot<<<8192, 256, 0, stream>>>(actA, W_a2, b_a2, scores);
    // 7. masked softmax over S (in place -> att_w)
    softmax_mask<<<B_, 256, 0, stream>>>(scores, masks, flag);
    // 8. attended[b,h] = sum_s mm * att_w             [64,512]
    attended_k<<<dim3(B_, HID_ / 256), 256, 0, stream>>>(actB, scores, attended);
    // 9. havg                                          [384,768]
    hist_avg<<<B_ * K_, 256, 0, stream>>>(phist, hcnt, havg);
    // 10. hproj = relu(havg @ W_hist + b_hist)         [384,512], K=768, split-K 8
    {
        const int nsp = 8, kps = EMB_ / nsp;
        gemm_splitk<<<dim3(8, 6, nsp), 256, 0, stream>>>(havg, W_hist, skbuf,
                                                         B_ * K_, HID_, EMB_, kps);
        reduce_k<1><<<(B_ * K_ * HID_ + 255) / 256, 256, 0, stream>>>(skbuf, b_hist, hproj,
                                                                      B_ * K_ * HID_, HID_, nsp);
    }
    // 11. sep0 = separate_images @ W_sep + b_sep       [384,512], K=2048, split-K 16
    {
        const int nsp = 16, kps = IMG_ / nsp;
        gemm_splitk<<<dim3(8, 6, nsp), 256, 0, stream>>>(sep_imgs, W_sep, skbuf,
                                                         B_ * K_, HID_, IMG_, kps);
        reduce_k<0><<<(B_ * K_ * HID_ + 255) / 256, 256, 0, stream>>>(skbuf, b_sep, sep0,
                                                                      B_ * K_ * HID_, HID_, nsp);
    }
    // 12. combine: relu, L2-normalize, dot with attended -> out [384]
    combine<<<B_ * K_, 256, 0, stream>>>(sep0, hproj, hcnt, attended, out);
}

// Round 4
// 316.238 us; speedup vs baseline: 5.9403x; 1.0869x over previous
//
#include <hip/hip_runtime.h>
#include <math.h>

#define B_    64
#define S_    512
#define EMB_  768
#define HID_  512
#define IMG_  2048
#define ATT_  512
#define K_    6
#define HL_   20

typedef __attribute__((ext_vector_type(8))) short bf16x8;
typedef __attribute__((ext_vector_type(4))) float f32x4;

__device__ __forceinline__ unsigned short f2b(float f) {
    unsigned int u = __float_as_uint(f);
    u += 0x7fffu + ((u >> 16) & 1u);          // RNE
    return (unsigned short)(u >> 16);
}
__device__ __forceinline__ float b2f(unsigned short s) {
    return __uint_as_float(((unsigned int)s) << 16);
}

#define GLD_LDS16(gp, lp)                                                        \
    __builtin_amdgcn_global_load_lds(                                            \
        (const __attribute__((address_space(1))) void*)(gp),                     \
        (__attribute__((address_space(3))) void*)(lp), 16, 0, 0)

// ---------------------------------------------------------------------------
// mask dtype probe: int32 0/1 values have bytes at (i&3)!=0 all zero.
__global__ __launch_bounds__(256)
void mask_detect(const unsigned char* __restrict__ m, int* __restrict__ flag, int nbytes) {
    __shared__ int found;
    if (threadIdx.x == 0) found = 0;
    __syncthreads();
    for (int i = threadIdx.x; i < nbytes; i += 256) {
        if ((i & 3) != 0 && m[i] != 0) found = 1;
    }
    __syncthreads();
    if (threadIdx.x == 0) *flag = found;
}

// ---------------------------------------------------------------------------
// fp32 -> bf16 bulk convert, 8 elems/thread/iter
__global__ __launch_bounds__(256)
void cvt_f32_bf16(const float* __restrict__ in, unsigned short* __restrict__ out, int n8) {
    int stride = gridDim.x * 256;
    for (int i = blockIdx.x * 256 + threadIdx.x; i < n8; i += stride) {
        float4 a = ((const float4*)in)[i * 2];
        float4 b = ((const float4*)in)[i * 2 + 1];
        unsigned short r[8] = {f2b(a.x), f2b(a.y), f2b(a.z), f2b(a.w),
                               f2b(b.x), f2b(b.y), f2b(b.z), f2b(b.w)};
        ((uint4*)out)[i] = *(uint4*)r;
    }
}

// ---------------------------------------------------------------------------
// Wt[n][k] = bf16(W[k][n]).  grid (Kd/32, N/32), block 256.
__global__ __launch_bounds__(256)
void transpose_cvt(const float* __restrict__ W, unsigned short* __restrict__ Wt,
                   int Kd, int N) {
    __shared__ float tile[32][33];
    int k0 = blockIdx.x * 32, n0 = blockIdx.y * 32;
    int tx = threadIdx.x & 31, ty = threadIdx.x >> 5;   // 32 x 8
    #pragma unroll
    for (int i = 0; i < 4; ++i)
        tile[ty + i * 8][tx] = W[(size_t)(k0 + ty + i * 8) * N + n0 + tx];
    __syncthreads();
    #pragma unroll
    for (int i = 0; i < 4; ++i)
        Wt[(size_t)(n0 + ty + i * 8) * Kd + k0 + tx] = f2b(tile[tx][ty + i * 8]);
}

// ---------------------------------------------------------------------------
// bf16 MFMA GEMM: C = act(A[M,K] @ Bt[N,K]^T + bias + row_add)
// 128x128 tile, BK=64, double-buffered LDS with stage-early prefetch,
// XOR-swizzled LDS layout (via pre-swizzled global source, rule #21),
// XCD-chunked bijective blockIdx swizzle (requires nwg % 8 == 0).
// 4 waves (2x2), 4x4 16x16x32 fragments, 2 K-substeps per tile.
// ACT: 0=none, 1=relu, 2=tanh.  M%128==0, N%128==0, Kd%64==0. Output bf16.
template<int ACT>
__global__ __launch_bounds__(256)
void gemm_bf16(const unsigned short* __restrict__ A, const unsigned short* __restrict__ Bt,
               const float* __restrict__ bias, const float* __restrict__ row_add,
               int row_div, unsigned short* __restrict__ Co, int M, int N, int Kd) {
    __shared__ unsigned short Als[2][128 * 64];
    __shared__ unsigned short Bls[2][128 * 64];
    const int tid = threadIdx.x;

    // XCD-chunked swizzle: consecutive hw blocks round-robin XCDs; give each
    // XCD a contiguous chunk of logical tiles so the 4 N-tiles sharing an
    // A-panel hit the same L2.
    const int nwg = gridDim.x;          // % 8 == 0 by construction
    const int cpx = nwg >> 3;
    const int lid = ((int)blockIdx.x & 7) * cpx + ((int)blockIdx.x >> 3);
    const int ntl = N >> 7;
    const int bn = (lid % ntl) << 7;
    const int bm = (lid / ntl) << 7;

    const int lane = tid & 63;
    const int wid = tid >> 6;
    const int wr = wid >> 1, wc = wid & 1;
    const int fr = lane & 15, hi = lane >> 4;

    f32x4 acc[4][4] = {};

    // staging decomposition: tile = 128 rows x 128 B = 1024 x 16B chunks,
    // 4 chunks/thread. stored col16 (g&7) holds logical col16 (g&7)^(row&7).
    int srow[4], scol[4];
    #pragma unroll
    for (int c = 0; c < 4; ++c) {
        int g = c * 256 + tid;
        srow[c] = g >> 3;
        scol[c] = (g & 7) ^ (srow[c] & 7);
    }

    const int nt = Kd >> 6;
    // prologue: stage tile 0 into buf 0
    #pragma unroll
    for (int c = 0; c < 4; ++c) {
        int g = c * 256 + tid;
        GLD_LDS16(A + (size_t)(bm + srow[c]) * Kd + scol[c] * 8, &Als[0][g * 8]);
        GLD_LDS16(Bt + (size_t)(bn + srow[c]) * Kd + scol[c] * 8, &Bls[0][g * 8]);
    }
    __syncthreads();

    for (int t = 0; t < nt; ++t) {
        const int buf = t & 1;
        if (t + 1 < nt) {                      // stage-early: issue next tile
            const int k0 = (t + 1) << 6;
            #pragma unroll
            for (int c = 0; c < 4; ++c) {
                int g = c * 256 + tid;
                GLD_LDS16(A + (size_t)(bm + srow[c]) * Kd + k0 + scol[c] * 8,
                          &Als[buf ^ 1][g * 8]);
                GLD_LDS16(Bt + (size_t)(bn + srow[c]) * Kd + k0 + scol[c] * 8,
                          &Bls[buf ^ 1][g * 8]);
            }
        }
        // compute on buf (its loads were drained by the previous barrier)
        #pragma unroll
        for (int kk = 0; kk < 2; ++kk) {
            bf16x8 af[4], bv[4];
            #pragma unroll
            for (int m = 0; m < 4; ++m) {
                int row = wr * 64 + m * 16 + fr;
                int sc = (kk * 4 + hi) ^ (fr & 7);
                af[m] = *(const bf16x8*)&Als[buf][row * 64 + sc * 8];
            }
            #pragma unroll
            for (int n = 0; n < 4; ++n) {
                int row = wc * 64 + n * 16 + fr;
                int sc = (kk * 4 + hi) ^ (fr & 7);
                bv[n] = *(const bf16x8*)&Bls[buf][row * 64 + sc * 8];
            }
            #pragma unroll
            for (int m = 0; m < 4; ++m)
                #pragma unroll
                for (int n = 0; n < 4; ++n)
                    acc[m][n] = __builtin_amdgcn_mfma_f32_16x16x32_bf16(af[m], bv[n], acc[m][n], 0, 0, 0);
        }
        __syncthreads();   // drains the t+1 stage (latency hidden under compute)
    }

    const int rg = hi;
    #pragma unroll
    for (int m = 0; m < 4; ++m) {
        #pragma unroll
        for (int n = 0; n < 4; ++n) {
            int col = bn + wc * 64 + n * 16 + fr;
            float badd = bias ? bias[col] : 0.f;
            #pragma unroll
            for (int r = 0; r < 4; ++r) {
                int row = bm + wr * 64 + m * 16 + rg * 4 + r;
                float x = acc[m][n][r] + badd;
                if (row_add) x += row_add[(size_t)(row / row_div) * N + col];
                if (ACT == 1) x = fmaxf(x, 0.f);
                if (ACT == 2) x = tanhf(x);
                Co[(size_t)row * N + col] = f2b(x);
            }
        }
    }
}

// ---------------------------------------------------------------------------
// split-K partial fp32 GEMM: P[z, m, n] = A[m, kz..kz+kps) @ W[.., n]
__global__ __launch_bounds__(256)
void gemm_splitk(const float* __restrict__ A, const float* __restrict__ W,
                 float* __restrict__ P, int M, int N, int Kd, int kps) {
    __shared__ float As[16][68];
    __shared__ float Ws[16][64];
    const int tid = threadIdx.x;
    const int bm = blockIdx.y * 64, bn = blockIdx.x * 64;
    const int ks = blockIdx.z;
    const int tx = tid & 15, ty = tid >> 4;
    const int arow = tid >> 2, akq = tid & 3;
    const int wk = tid >> 4, wnq = tid & 15;

    float acc[4][4] = {};
    const int kbeg = ks * kps, kend = kbeg + kps;

    for (int k0 = kbeg; k0 < kend; k0 += 16) {
        float4 av = *(const float4*)&A[(size_t)(bm + arow) * Kd + k0 + akq * 4];
        float4 wv = *(const float4*)&W[(size_t)(k0 + wk) * N + bn + wnq * 4];
        As[akq * 4 + 0][arow] = av.x;
        As[akq * 4 + 1][arow] = av.y;
        As[akq * 4 + 2][arow] = av.z;
        As[akq * 4 + 3][arow] = av.w;
        *(float4*)&Ws[wk][wnq * 4] = wv;
        __syncthreads();
        #pragma unroll
        for (int kk = 0; kk < 16; ++kk) {
            float4 a4 = *(const float4*)&As[kk][ty * 4];
            float4 b4 = *(const float4*)&Ws[kk][tx * 4];
            float a_[4] = {a4.x, a4.y, a4.z, a4.w};
            float b_[4] = {b4.x, b4.y, b4.z, b4.w};
            #pragma unroll
            for (int i = 0; i < 4; ++i)
                #pragma unroll
                for (int j = 0; j < 4; ++j)
                    acc[i][j] += a_[i] * b_[j];
        }
        __syncthreads();
    }

    float* Pbase = P + (size_t)ks * M * N;
    #pragma unroll
    for (int i = 0; i < 4; ++i) {
        int row = bm + ty * 4 + i;
        float4 v = {acc[i][0], acc[i][1], acc[i][2], acc[i][3]};
        *(float4*)&Pbase[(size_t)row * N + bn + tx * 4] = v;
    }
}

// ---------------------------------------------------------------------------
template<int ACT>
__global__ __launch_bounds__(256)
void reduce_k(const float* __restrict__ P, const float* __restrict__ bias,
              float* __restrict__ C, int MN, int N, int nsplit) {
    int idx = blockIdx.x * 256 + threadIdx.x;
    if (idx >= MN) return;
    float s = 0.f;
    for (int z = 0; z < nsplit; ++z) s += P[(size_t)z * MN + idx];
    if (bias) s += bias[idx & (N - 1)];
    if (ACT == 1) s = fmaxf(s, 0.f);
    C[idx] = s;
}

// ---------------------------------------------------------------------------
// scores[row] = bf16(t[row,:]) . W_a2 + b_a2   (one wave per row)
__global__ __launch_bounds__(256)
void score_dot(const unsigned short* __restrict__ t, const float* __restrict__ W_a2,
               const float* __restrict__ b_a2, float* __restrict__ scores) {
    int row = blockIdx.x * 4 + (threadIdx.x >> 6);
    int lane = threadIdx.x & 63;
    const unsigned short* tr = t + (size_t)row * ATT_;
    float s = 0.f;
    #pragma unroll
    for (int i = 0; i < ATT_ / 64; ++i)
        s += b2f(tr[lane + i * 64]) * W_a2[lane + i * 64];
    #pragma unroll
    for (int off = 32; off; off >>= 1) s += __shfl_down(s, off, 64);
    if (lane == 0) scores[row] = s + b_a2[0];
}

// ---------------------------------------------------------------------------
__global__ __launch_bounds__(256)
void softmax_mask(float* __restrict__ scores, const void* __restrict__ masks_raw,
                  const int* __restrict__ flag) {
    int b = blockIdx.x, tid = threadIdx.x;
    bool isb = (*flag) != 0;
    const unsigned char* mb = (const unsigned char*)masks_raw;
    const int* mi = (const int*)masks_raw;
    int lane = tid & 63, wv = tid >> 6;
    __shared__ float red[4], red2[4];

    float m = -INFINITY;
    for (int s = tid; s < S_; s += 256) {
        int idx = b * S_ + s;
        bool mk = isb ? (mb[idx] != 0) : (mi[idx] != 0);
        float v = mk ? -INFINITY : scores[idx];
        scores[idx] = v;
        m = fmaxf(m, v);
    }
    #pragma unroll
    for (int off = 32; off; off >>= 1) m = fmaxf(m, __shfl_down(m, off, 64));
    if (lane == 0) red[wv] = m;
    __syncthreads();
    if (tid == 0) red[0] = fmaxf(fmaxf(red[0], red[1]), fmaxf(red[2], red[3]));
    __syncthreads();
    float Mx = red[0];

    float sum = 0.f;
    for (int s = tid; s < S_; s += 256) {
        int idx = b * S_ + s;
        float e = expf(scores[idx] - Mx);
        scores[idx] = e;
        sum += e;
    }
    #pragma unroll
    for (int off = 32; off; off >>= 1) sum += __shfl_down(sum, off, 64);
    if (lane == 0) red2[wv] = sum;
    __syncthreads();
    if (tid == 0) red2[0] = red2[0] + red2[1] + red2[2] + red2[3];
    __syncthreads();
    float inv = 1.f / red2[0];
    for (int s = tid; s < S_; s += 256) scores[b * S_ + s] *= inv;
}

// ---------------------------------------------------------------------------
// attended[b,h] = sum_s bf16(mm[b,s,h]) * att_w[b,s]
__global__ __launch_bounds__(256)
void attended_k(const unsigned short* __restrict__ mm, const float* __restrict__ att_w,
                float* __restrict__ attended) {
    int b = blockIdx.x;
    int h = blockIdx.y * 256 + threadIdx.x;
    __shared__ float w[S_];
    for (int s = threadIdx.x; s < S_; s += 256) w[s] = att_w[b * S_ + s];
    __syncthreads();
    float acc = 0.f;
    for (int s = 0; s < S_; ++s)
        acc += b2f(mm[((size_t)b * S_ + s) * HID_ + h]) * w[s];
    attended[b * HID_ + h] = acc;
}

// ---------------------------------------------------------------------------
__global__ __launch_bounds__(256)
void hist_avg(const float* __restrict__ ph, const int* __restrict__ hcnt,
              float* __restrict__ havg) {
    int bk = blockIdx.x;
    int cnt = hcnt[bk];
    float denom = (float)(cnt > 1 ? cnt : 1);
    const float* base = ph + (size_t)bk * HL_ * EMB_;
    for (int e = threadIdx.x; e < EMB_; e += 256) {
        float s = 0.f;
        for (int l = 0; l < cnt; ++l) s += base[l * EMB_ + e];
        havg[bk * EMB_ + e] = s / denom;
    }
}

// ---------------------------------------------------------------------------
__global__ __launch_bounds__(256)
void combine(const float* __restrict__ sep0, const float* __restrict__ hproj,
             const int* __restrict__ hcnt, const float* __restrict__ attended,
             float* __restrict__ out) {
    int bk = blockIdx.x, tid = threadIdx.x;
    int b = bk / K_;
    int cnt = hcnt[bk];
    float sq = 0.f, dt = 0.f;
    #pragma unroll
    for (int i = 0; i < HID_ / 256; ++i) {
        int h = tid + i * 256;
        float v = sep0[bk * HID_ + h];
        if (cnt > 0) v += hproj[bk * HID_ + h];
        v = fmaxf(v, 0.f);
        sq += v * v;
        dt += v * attended[b * HID_ + h];
    }
    #pragma unroll
    for (int off = 32; off; off >>= 1) {
        sq += __shfl_down(sq, off, 64);
        dt += __shfl_down(dt, off, 64);
    }
    __shared__ float rs[4], rd[4];
    int lane = tid & 63, wv = tid >> 6;
    if (lane == 0) { rs[wv] = sq; rd[wv] = dt; }
    __syncthreads();
    if (tid == 0) {
        float Sq = rs[0] + rs[1] + rs[2] + rs[3];
        float Dt = rd[0] + rd[1] + rd[2] + rd[3];
        float norm = fmaxf(sqrtf(Sq), 1e-12f);
        out[bk] = Dt / norm;
    }
}

// ---------------------------------------------------------------------------
extern "C" void kernel_launch(void* const* d_in, const int* in_sizes, int n_in,
                              void* d_out, int out_size, void* d_ws, size_t ws_size,
                              hipStream_t stream) {
    const float* reps     = (const float*)d_in[0];
    const float* sep_imgs = (const float*)d_in[2];
    const float* vctx     = (const float*)d_in[3];
    const float* phist    = (const float*)d_in[4];
    const int*   hcnt     = (const int*)d_in[5];
    const void*  masks    = d_in[6];
    const float* W_sep = (const float*)d_in[7];
    const float* b_sep = (const float*)d_in[8];
    const float* W_e2h = (const float*)d_in[9];
    const float* b_e2h = (const float*)d_in[10];
    const float* W_hist = (const float*)d_in[11];
    const float* b_hist = (const float*)d_in[12];
    const float* W_ctx = (const float*)d_in[13];
    const float* b_ctx = (const float*)d_in[14];
    const float* W_mm = (const float*)d_in[15];
    const float* b_mm = (const float*)d_in[16];
    const float* W_a1 = (const float*)d_in[17];
    const float* b_a1 = (const float*)d_in[18];
    const float* W_a2 = (const float*)d_in[19];
    const float* b_a2 = (const float*)d_in[20];
    float* out = (float*)d_out;

    const size_t MS = (size_t)B_ * S_;                     // 32768

    // ---- workspace layout ----
    unsigned short* repsb = (unsigned short*)d_ws;         // [32768*768] bf16
    unsigned short* actA  = repsb + MS * EMB_;             // [32768*512] input_reps, later t
    unsigned short* actB  = actA + MS * HID_;              // [32768*512] mm
    unsigned short* WtE2H = actB + MS * HID_;              // [512*768]
    unsigned short* WtMM  = WtE2H + (size_t)EMB_ * HID_;   // [512*512]
    unsigned short* WtA1  = WtMM + (size_t)HID_ * HID_;    // [512*512]
    float* skbuf = (float*)(WtA1 + (size_t)HID_ * HID_);   // split-K scratch (<=16*384*512)
    float* ctx   = skbuf + (size_t)16 * 384 * 512;
    float* ctx2  = ctx + B_ * HID_;
    float* scores = ctx2 + B_ * HID_;                      // [B,S]
    float* attended = scores + MS;
    float* sep0  = attended + B_ * HID_;
    float* havg  = sep0 + B_ * K_ * HID_;
    float* hproj = havg + B_ * K_ * EMB_;
    int*   flag  = (int*)(hproj + B_ * K_ * HID_);

    // 0. mask dtype probe
    mask_detect<<<1, 256, 0, stream>>>((const unsigned char*)masks, flag, 8192);

    // 0b. conversions for MFMA path
    cvt_f32_bf16<<<2048, 256, 0, stream>>>(reps, repsb, (int)(MS * EMB_ / 8));
    transpose_cvt<<<dim3(EMB_ / 32, HID_ / 32), 256, 0, stream>>>(W_e2h, WtE2H, EMB_, HID_);
    transpose_cvt<<<dim3(HID_ / 32, HID_ / 32), 256, 0, stream>>>(W_mm, WtMM, HID_, HID_);
    transpose_cvt<<<dim3(HID_ / 32, HID_ / 32), 256, 0, stream>>>(W_a1, WtA1, HID_, HID_);

    // 1. ctx = relu(visual_context @ W_ctx + b_ctx)   [64,512], K=12288, split-K 64
    {
        const int nsp = 64, kps = (K_ * IMG_) / nsp;
        gemm_splitk<<<dim3(8, 1, nsp), 256, 0, stream>>>(vctx, W_ctx, skbuf,
                                                         B_, HID_, K_ * IMG_, kps);
        reduce_k<1><<<(B_ * HID_ + 255) / 256, 256, 0, stream>>>(skbuf, b_ctx, ctx,
                                                                 B_ * HID_, HID_, nsp);
    }
    // 2. ctx2 = ctx @ W_mm[H:,:] + b_mm               [64,512], K=512, split-K 8
    {
        const int nsp = 8, kps = HID_ / nsp;
        gemm_splitk<<<dim3(8, 1, nsp), 256, 0, stream>>>(ctx, W_mm + (size_t)HID_ * HID_,
                                                         skbuf, B_, HID_, HID_, kps);
        reduce_k<0><<<(B_ * HID_ + 255) / 256, 256, 0, stream>>>(skbuf, b_mm, ctx2,
                                                                 B_ * HID_, HID_, nsp);
    }
    // grid for the three big GEMMs: (M/128)*(N/128) = 256*4 = 1024 (% 8 == 0)
    const int big_grid = ((int)MS / 128) * (HID_ / 128);
    // 3. input_reps = relu(reps @ W_e2h + b_e2h)      [32768,512] bf16 MFMA
    gemm_bf16<1><<<big_grid, 256, 0, stream>>>(repsb, WtE2H, b_e2h, nullptr, 1,
                                               actA, (int)MS, HID_, EMB_);
    // 4. mm = relu(input_reps @ W_mm[:H,:] + ctx2[b]) [32768,512] bf16 MFMA
    gemm_bf16<1><<<big_grid, 256, 0, stream>>>(actA, WtMM, nullptr, ctx2, S_,
                                               actB, (int)MS, HID_, HID_);
    // 5. t = tanh(mm @ W_a1 + b_a1)  (reuses actA)    [32768,512] bf16 MFMA
    gemm_bf16<2><<<big_grid, 256, 0, stream>>>(actB, WtA1, b_a1, nullptr, 1,
                                               actA, (int)MS, ATT_, HID_);
    // 6. scores = t . W_a2 + b_a2
    score_dot<<<8192, 256, 0, stream>>>(actA, W_a2, b_a2, scores);
    // 7. masked softmax over S (in place -> att_w)
    softmax_mask<<<B_, 256, 0, stream>>>(scores, masks, flag);
    // 8. attended[b,h] = sum_s mm * att_w             [64,512]
    attended_k<<<dim3(B_, HID_ / 256), 256, 0, stream>>>(actB, scores, attended);
    // 9. havg                                          [384,768]
    hist_avg<<<B_ * K_, 256, 0, stream>>>(phist, hcnt, havg);
    // 10. hproj = relu(havg @ W_hist + b_hist)         [384,512], K=768, split-K 8
    {
        const int nsp = 8, kps = EMB_ / nsp;
        gemm_splitk<<<dim3(8, 6, nsp), 256, 0, stream>>>(havg, W_hist, skbuf,
                                                         B_ * K_, HID_, EMB_, kps);
        reduce_k<1><<<(B_ * K_ * HID_ + 255) / 256, 256, 0, stream>>>(skbuf, b_hist, hproj,
                                                                      B_ * K_ * HID_, HID_, nsp);
    }
    // 11. sep0 = separate_images @ W_sep + b_sep       [384,512], K=2048, split-K 16
    {
        const int nsp = 16, kps = IMG_ / nsp;
        gemm_splitk<<<dim3(8, 6, nsp), 256, 0, stream>>>(sep_imgs, W_sep, skbuf,
                                                         B_ * K_, HID_, IMG_, kps);
        reduce_k<0><<<(B_ * K_ * HID_ + 255) / 256, 256, 0, stream>>>(skbuf, b_sep, sep0,
                                                                      B_ * K_ * HID_, HID_, nsp);
    }
    // 12. combine: relu, L2-normalize, dot with attended -> out [384]
    combine<<<B_ * K_, 256, 0, stream>>>(sep0, hproj, hcnt, attended, out);
}

// Round 5
// 262.704 us; speedup vs baseline: 7.1508x; 1.2038x over previous
//
#include <hip/hip_runtime.h>
#include <math.h>

#define B_    64
#define S_    512
#define EMB_  768
#define HID_  512
#define IMG_  2048
#define ATT_  512
#define K_    6
#define HL_   20
#define MS_   (B_ * S_)            // 32768

typedef __attribute__((ext_vector_type(8))) short bf16x8;
typedef __attribute__((ext_vector_type(4))) float f32x4;

__device__ __forceinline__ unsigned short f2b(float f) {
    unsigned int u = __float_as_uint(f);
    u += 0x7fffu + ((u >> 16) & 1u);          // RNE
    return (unsigned short)(u >> 16);
}
__device__ __forceinline__ unsigned int pk_bf16(float lo, float hi) {
    unsigned int r;
    asm volatile("v_cvt_pk_bf16_f32 %0, %1, %2" : "=v"(r) : "v"(lo), "v"(hi));
    return r;
}

#define GLD_LDS16(gp, lp)                                                        \
    __builtin_amdgcn_global_load_lds(                                            \
        (const __attribute__((address_space(1))) void*)(gp),                     \
        (__attribute__((address_space(3))) void*)(lp), 16, 0, 0)

// ---------------------------------------------------------------------------
// prep: z=0..2 -> transpose+cvt of W_e2h / W_mm[:H] / W_a1 ; z=3 -> mask probe
__global__ __launch_bounds__(256)
void prep(const float* __restrict__ W_e2h, const float* __restrict__ W_mm,
          const float* __restrict__ W_a1,
          unsigned short* __restrict__ WtE2H, unsigned short* __restrict__ WtMM,
          unsigned short* __restrict__ WtA1,
          const unsigned char* __restrict__ masks, int* __restrict__ flag) {
    const int z = blockIdx.z;
    if (z == 3) {
        if (blockIdx.x != 0 || blockIdx.y != 0) return;
        __shared__ int found;
        if (threadIdx.x == 0) found = 0;
        __syncthreads();
        for (int i = threadIdx.x; i < 8192; i += 256)
            if ((i & 3) != 0 && masks[i] != 0) found = 1;
        __syncthreads();
        if (threadIdx.x == 0) *flag = found;
        return;
    }
    const float* W;
    unsigned short* Wt;
    int Kd;
    if (z == 0)      { W = W_e2h; Wt = WtE2H; Kd = EMB_; }
    else if (z == 1) { W = W_mm;  Wt = WtMM;  Kd = HID_; }
    else             { W = W_a1;  Wt = WtA1;  Kd = HID_; }
    if ((int)blockIdx.x * 32 >= Kd) return;

    __shared__ float tile[32][33];
    int k0 = blockIdx.x * 32, n0 = blockIdx.y * 32;
    int tx = threadIdx.x & 31, ty = threadIdx.x >> 5;   // 32 x 8
    #pragma unroll
    for (int i = 0; i < 4; ++i)
        tile[ty + i * 8][tx] = W[(size_t)(k0 + ty + i * 8) * HID_ + n0 + tx];
    __syncthreads();
    #pragma unroll
    for (int i = 0; i < 4; ++i)
        Wt[(size_t)(n0 + ty + i * 8) * Kd + k0 + tx] = f2b(tile[tx][ty + i * 8]);
}

// ---------------------------------------------------------------------------
// XCD-chunked bijective block swizzle helper (nwg % 8 == 0).
__device__ __forceinline__ void tile_coords(int N, int& bm, int& bn) {
    const int nwg = gridDim.x;
    const int cpx = nwg >> 3;
    const int lid = ((int)blockIdx.x & 7) * cpx + ((int)blockIdx.x >> 3);
    const int ntl = N >> 7;
    bn = (lid % ntl) << 7;
    bm = (lid / ntl) << 7;
}

// ---------------------------------------------------------------------------
// bf16 MFMA GEMM (A already bf16): C = act(A @ Bt^T + bias + row_add)
// 128x128 tile, BK=64, dbuf stage-early, XOR-swizzled LDS. Output bf16.
template<int ACT>
__global__ __launch_bounds__(256)
void gemm_bf16(const unsigned short* __restrict__ A, const unsigned short* __restrict__ Bt,
               const float* __restrict__ bias, const float* __restrict__ row_add,
               int row_div, unsigned short* __restrict__ Co, int M, int N, int Kd) {
    __shared__ unsigned short Als[2][128 * 64];
    __shared__ unsigned short Bls[2][128 * 64];
    const int tid = threadIdx.x;
    int bm, bn; tile_coords(N, bm, bn);
    const int lane = tid & 63, wid = tid >> 6;
    const int wr = wid >> 1, wc = wid & 1;
    const int fr = lane & 15, hi = lane >> 4;

    f32x4 acc[4][4] = {};
    int srow[4], scol[4];
    #pragma unroll
    for (int c = 0; c < 4; ++c) {
        int g = c * 256 + tid;
        srow[c] = g >> 3;
        scol[c] = (g & 7) ^ (srow[c] & 7);
    }

    const int nt = Kd >> 6;
    #pragma unroll
    for (int c = 0; c < 4; ++c) {
        int g = c * 256 + tid;
        GLD_LDS16(A + (size_t)(bm + srow[c]) * Kd + scol[c] * 8, &Als[0][g * 8]);
        GLD_LDS16(Bt + (size_t)(bn + srow[c]) * Kd + scol[c] * 8, &Bls[0][g * 8]);
    }
    __syncthreads();

    for (int t = 0; t < nt; ++t) {
        const int buf = t & 1;
        if (t + 1 < nt) {
            const int k0 = (t + 1) << 6;
            #pragma unroll
            for (int c = 0; c < 4; ++c) {
                int g = c * 256 + tid;
                GLD_LDS16(A + (size_t)(bm + srow[c]) * Kd + k0 + scol[c] * 8,
                          &Als[buf ^ 1][g * 8]);
                GLD_LDS16(Bt + (size_t)(bn + srow[c]) * Kd + k0 + scol[c] * 8,
                          &Bls[buf ^ 1][g * 8]);
            }
        }
        #pragma unroll
        for (int kk = 0; kk < 2; ++kk) {
            bf16x8 af[4], bv[4];
            #pragma unroll
            for (int m = 0; m < 4; ++m) {
                int row = wr * 64 + m * 16 + fr;
                int sc = (kk * 4 + hi) ^ (fr & 7);
                af[m] = *(const bf16x8*)&Als[buf][row * 64 + sc * 8];
            }
            #pragma unroll
            for (int n = 0; n < 4; ++n) {
                int row = wc * 64 + n * 16 + fr;
                int sc = (kk * 4 + hi) ^ (fr & 7);
                bv[n] = *(const bf16x8*)&Bls[buf][row * 64 + sc * 8];
            }
            #pragma unroll
            for (int m = 0; m < 4; ++m)
                #pragma unroll
                for (int n = 0; n < 4; ++n)
                    acc[m][n] = __builtin_amdgcn_mfma_f32_16x16x32_bf16(af[m], bv[n], acc[m][n], 0, 0, 0);
        }
        __syncthreads();
    }

    #pragma unroll
    for (int m = 0; m < 4; ++m) {
        #pragma unroll
        for (int n = 0; n < 4; ++n) {
            int col = bn + wc * 64 + n * 16 + fr;
            float badd = bias ? bias[col] : 0.f;
            #pragma unroll
            for (int r = 0; r < 4; ++r) {
                int row = bm + wr * 64 + m * 16 + hi * 4 + r;
                float x = acc[m][n][r] + badd;
                if (row_add) x += row_add[(size_t)(row / row_div) * N + col];
                if (ACT == 1) x = fmaxf(x, 0.f);
                if (ACT == 2) x = tanhf(x);
                Co[(size_t)row * N + col] = f2b(x);
            }
        }
    }
}

// ---------------------------------------------------------------------------
// fp32-input MFMA GEMM: A fp32 reg-staged (convert+ds_write), Bt bf16 gld_lds.
template<int ACT>
__global__ __launch_bounds__(256)
void gemm_f32in(const float* __restrict__ A, const unsigned short* __restrict__ Bt,
                const float* __restrict__ bias, unsigned short* __restrict__ Co,
                int M, int N, int Kd) {
    __shared__ unsigned short Als[2][128 * 64];
    __shared__ unsigned short Bls[2][128 * 64];
    const int tid = threadIdx.x;
    int bm, bn; tile_coords(N, bm, bn);
    const int lane = tid & 63, wid = tid >> 6;
    const int wr = wid >> 1, wc = wid & 1;
    const int fr = lane & 15, hi = lane >> 4;

    f32x4 acc[4][4] = {};
    int srow[4], lcol[4], scol[4];
    #pragma unroll
    for (int c = 0; c < 4; ++c) {
        int g = c * 256 + tid;
        srow[c] = g >> 3;
        lcol[c] = g & 7;
        scol[c] = lcol[c] ^ (srow[c] & 7);
    }

    const int nt = Kd >> 6;
    float4 ra[8];

    // prologue: tile 0
    #pragma unroll
    for (int c = 0; c < 4; ++c) {
        int g = c * 256 + tid;
        GLD_LDS16(Bt + (size_t)(bn + srow[c]) * Kd + scol[c] * 8, &Bls[0][g * 8]);
        const float* p = A + (size_t)(bm + srow[c]) * Kd + lcol[c] * 8;
        ra[2 * c]     = *(const float4*)p;
        ra[2 * c + 1] = *(const float4*)(p + 4);
    }
    #pragma unroll
    for (int c = 0; c < 4; ++c) {
        uint4 u;
        u.x = pk_bf16(ra[2*c].x,   ra[2*c].y);
        u.y = pk_bf16(ra[2*c].z,   ra[2*c].w);
        u.z = pk_bf16(ra[2*c+1].x, ra[2*c+1].y);
        u.w = pk_bf16(ra[2*c+1].z, ra[2*c+1].w);
        *(uint4*)&Als[0][(srow[c] * 8 + scol[c]) * 8] = u;
    }
    __syncthreads();

    for (int t = 0; t < nt; ++t) {
        const int buf = t & 1;
        if (t + 1 < nt) {
            const int k0 = (t + 1) << 6;
            #pragma unroll
            for (int c = 0; c < 4; ++c) {
                int g = c * 256 + tid;
                GLD_LDS16(Bt + (size_t)(bn + srow[c]) * Kd + k0 + scol[c] * 8,
                          &Bls[buf ^ 1][g * 8]);
                const float* p = A + (size_t)(bm + srow[c]) * Kd + k0 + lcol[c] * 8;
                ra[2 * c]     = *(const float4*)p;
                ra[2 * c + 1] = *(const float4*)(p + 4);
            }
        }
        #pragma unroll
        for (int kk = 0; kk < 2; ++kk) {
            bf16x8 af[4], bv[4];
            #pragma unroll
            for (int m = 0; m < 4; ++m) {
                int row = wr * 64 + m * 16 + fr;
                int sc = (kk * 4 + hi) ^ (fr & 7);
                af[m] = *(const bf16x8*)&Als[buf][row * 64 + sc * 8];
            }
            #pragma unroll
            for (int n = 0; n < 4; ++n) {
                int row = wc * 64 + n * 16 + fr;
                int sc = (kk * 4 + hi) ^ (fr & 7);
                bv[n] = *(const bf16x8*)&Bls[buf][row * 64 + sc * 8];
            }
            #pragma unroll
            for (int m = 0; m < 4; ++m)
                #pragma unroll
                for (int n = 0; n < 4; ++n)
                    acc[m][n] = __builtin_amdgcn_mfma_f32_16x16x32_bf16(af[m], bv[n], acc[m][n], 0, 0, 0);
        }
        if (t + 1 < nt) {
            #pragma unroll
            for (int c = 0; c < 4; ++c) {
                uint4 u;
                u.x = pk_bf16(ra[2*c].x,   ra[2*c].y);
                u.y = pk_bf16(ra[2*c].z,   ra[2*c].w);
                u.z = pk_bf16(ra[2*c+1].x, ra[2*c+1].y);
                u.w = pk_bf16(ra[2*c+1].z, ra[2*c+1].w);
                *(uint4*)&Als[buf ^ 1][(srow[c] * 8 + scol[c]) * 8] = u;
            }
        }
        __syncthreads();
    }

    #pragma unroll
    for (int m = 0; m < 4; ++m) {
        #pragma unroll
        for (int n = 0; n < 4; ++n) {
            int col = bn + wc * 64 + n * 16 + fr;
            float badd = bias ? bias[col] : 0.f;
            #pragma unroll
            for (int r = 0; r < 4; ++r) {
                int row = bm + wr * 64 + m * 16 + hi * 4 + r;
                float x = acc[m][n][r] + badd;
                if (ACT == 1) x = fmaxf(x, 0.f);
                Co[(size_t)row * N + col] = f2b(x);
            }
        }
    }
}

// ---------------------------------------------------------------------------
// GEMM5 + score fusion: computes t = tanh(A @ Bt^T + b_a1) in-register and
// writes per-(coltile,wave) partial scores: scores8[slot][row] = sum_cols t*W_a2.
__global__ __launch_bounds__(256)
void gemm_score(const unsigned short* __restrict__ A, const unsigned short* __restrict__ Bt,
                const float* __restrict__ b_a1, const float* __restrict__ W_a2,
                float* __restrict__ scores8, int M, int N, int Kd) {
    __shared__ unsigned short Als[2][128 * 64];
    __shared__ unsigned short Bls[2][128 * 64];
    const int tid = threadIdx.x;
    int bm, bn; tile_coords(N, bm, bn);
    const int lane = tid & 63, wid = tid >> 6;
    const int wr = wid >> 1, wc = wid & 1;
    const int fr = lane & 15, hi = lane >> 4;

    f32x4 acc[4][4] = {};
    int srow[4], scol[4];
    #pragma unroll
    for (int c = 0; c < 4; ++c) {
        int g = c * 256 + tid;
        srow[c] = g >> 3;
        scol[c] = (g & 7) ^ (srow[c] & 7);
    }

    const int nt = Kd >> 6;
    #pragma unroll
    for (int c = 0; c < 4; ++c) {
        int g = c * 256 + tid;
        GLD_LDS16(A + (size_t)(bm + srow[c]) * Kd + scol[c] * 8, &Als[0][g * 8]);
        GLD_LDS16(Bt + (size_t)(bn + srow[c]) * Kd + scol[c] * 8, &Bls[0][g * 8]);
    }
    __syncthreads();

    for (int t = 0; t < nt; ++t) {
        const int buf = t & 1;
        if (t + 1 < nt) {
            const int k0 = (t + 1) << 6;
            #pragma unroll
            for (int c = 0; c < 4; ++c) {
                int g = c * 256 + tid;
                GLD_LDS16(A + (size_t)(bm + srow[c]) * Kd + k0 + scol[c] * 8,
                          &Als[buf ^ 1][g * 8]);
                GLD_LDS16(Bt + (size_t)(bn + srow[c]) * Kd + k0 + scol[c] * 8,
                          &Bls[buf ^ 1][g * 8]);
            }
        }
        #pragma unroll
        for (int kk = 0; kk < 2; ++kk) {
            bf16x8 af[4], bv[4];
            #pragma unroll
            for (int m = 0; m < 4; ++m) {
                int row = wr * 64 + m * 16 + fr;
                int sc = (kk * 4 + hi) ^ (fr & 7);
                af[m] = *(const bf16x8*)&Als[buf][row * 64 + sc * 8];
            }
            #pragma unroll
            for (int n = 0; n < 4; ++n) {
                int row = wc * 64 + n * 16 + fr;
                int sc = (kk * 4 + hi) ^ (fr & 7);
                bv[n] = *(const bf16x8*)&Bls[buf][row * 64 + sc * 8];
            }
            #pragma unroll
            for (int m = 0; m < 4; ++m)
                #pragma unroll
                for (int n = 0; n < 4; ++n)
                    acc[m][n] = __builtin_amdgcn_mfma_f32_16x16x32_bf16(af[m], bv[n], acc[m][n], 0, 0, 0);
        }
        __syncthreads();
    }

    float ba[4], wa[4];
    #pragma unroll
    for (int n = 0; n < 4; ++n) {
        int col = bn + wc * 64 + n * 16 + fr;
        ba[n] = b_a1[col];
        wa[n] = W_a2[col];
    }
    const int slot = (bn >> 7) * 2 + wc;
    #pragma unroll
    for (int m = 0; m < 4; ++m) {
        #pragma unroll
        for (int r = 0; r < 4; ++r) {
            float p = 0.f;
            #pragma unroll
            for (int n = 0; n < 4; ++n)
                p += tanhf(acc[m][n][r] + ba[n]) * wa[n];
            p += __shfl_xor(p, 1, 64);
            p += __shfl_xor(p, 2, 64);
            p += __shfl_xor(p, 4, 64);
            p += __shfl_xor(p, 8, 64);
            if (fr == 0)
                scores8[(size_t)slot * M + bm + wr * 64 + m * 16 + hi * 4 + r] = p;
        }
    }
}

// ---------------------------------------------------------------------------
// split-K partial fp32 GEMM: P[z, m, n] = A[m, kz..kz+kps) @ W[.., n]
__global__ __launch_bounds__(256)
void gemm_splitk(const float* __restrict__ A, const float* __restrict__ W,
                 float* __restrict__ P, int M, int N, int Kd, int kps) {
    __shared__ float As[16][68];
    __shared__ float Ws[16][64];
    const int tid = threadIdx.x;
    const int bm = blockIdx.y * 64, bn = blockIdx.x * 64;
    const int ks = blockIdx.z;
    const int tx = tid & 15, ty = tid >> 4;
    const int arow = tid >> 2, akq = tid & 3;
    const int wk = tid >> 4, wnq = tid & 15;

    float acc[4][4] = {};
    const int kbeg = ks * kps, kend = kbeg + kps;

    for (int k0 = kbeg; k0 < kend; k0 += 16) {
        float4 av = *(const float4*)&A[(size_t)(bm + arow) * Kd + k0 + akq * 4];
        float4 wv = *(const float4*)&W[(size_t)(k0 + wk) * N + bn + wnq * 4];
        As[akq * 4 + 0][arow] = av.x;
        As[akq * 4 + 1][arow] = av.y;
        As[akq * 4 + 2][arow] = av.z;
        As[akq * 4 + 3][arow] = av.w;
        *(float4*)&Ws[wk][wnq * 4] = wv;
        __syncthreads();
        #pragma unroll
        for (int kk = 0; kk < 16; ++kk) {
            float4 a4 = *(const float4*)&As[kk][ty * 4];
            float4 b4 = *(const float4*)&Ws[kk][tx * 4];
            float a_[4] = {a4.x, a4.y, a4.z, a4.w};
            float b_[4] = {b4.x, b4.y, b4.z, b4.w};
            #pragma unroll
            for (int i = 0; i < 4; ++i)
                #pragma unroll
                for (int j = 0; j < 4; ++j)
                    acc[i][j] += a_[i] * b_[j];
        }
        __syncthreads();
    }

    float* Pbase = P + (size_t)ks * M * N;
    #pragma unroll
    for (int i = 0; i < 4; ++i) {
        int row = bm + ty * 4 + i;
        float4 v = {acc[i][0], acc[i][1], acc[i][2], acc[i][3]};
        *(float4*)&Pbase[(size_t)row * N + bn + tx * 4] = v;
    }
}

// ---------------------------------------------------------------------------
template<int ACT>
__global__ __launch_bounds__(256)
void reduce_k(const float* __restrict__ P, const float* __restrict__ bias,
              float* __restrict__ C, int MN, int N, int nsplit) {
    int idx = blockIdx.x * 256 + threadIdx.x;
    if (idx >= MN) return;
    float s = 0.f;
    for (int z = 0; z < nsplit; ++z) s += P[(size_t)z * MN + idx];
    if (bias) s += bias[idx & (N - 1)];
    if (ACT == 1) s = fmaxf(s, 0.f);
    C[idx] = s;
}

// ---------------------------------------------------------------------------
// masked softmax over S per batch; input = sum of 8 score slots + b_a2.
__global__ __launch_bounds__(256)
void softmax8(const float* __restrict__ scores8, const float* __restrict__ b_a2,
              const void* __restrict__ masks_raw, const int* __restrict__ flag,
              float* __restrict__ attw) {
    int b = blockIdx.x, tid = threadIdx.x;
    bool isb = (*flag) != 0;
    const unsigned char* mb = (const unsigned char*)masks_raw;
    const int* mi = (const int*)masks_raw;
    int lane = tid & 63, wv = tid >> 6;
    __shared__ float red[4], red2[4];
    float bias = b_a2[0];

    float m = -INFINITY;
    for (int s = tid; s < S_; s += 256) {
        int idx = b * S_ + s;
        float v = bias;
        #pragma unroll
        for (int z = 0; z < 8; ++z) v += scores8[(size_t)z * MS_ + idx];
        bool mk = isb ? (mb[idx] != 0) : (mi[idx] != 0);
        v = mk ? -INFINITY : v;
        attw[idx] = v;
        m = fmaxf(m, v);
    }
    #pragma unroll
    for (int off = 32; off; off >>= 1) m = fmaxf(m, __shfl_down(m, off, 64));
    if (lane == 0) red[wv] = m;
    __syncthreads();
    if (tid == 0) red[0] = fmaxf(fmaxf(red[0], red[1]), fmaxf(red[2], red[3]));
    __syncthreads();
    float Mx = red[0];

    float sum = 0.f;
    for (int s = tid; s < S_; s += 256) {
        int idx = b * S_ + s;
        float e = expf(attw[idx] - Mx);
        attw[idx] = e;
        sum += e;
    }
    #pragma unroll
    for (int off = 32; off; off >>= 1) sum += __shfl_down(sum, off, 64);
    if (lane == 0) red2[wv] = sum;
    __syncthreads();
    if (tid == 0) red2[0] = red2[0] + red2[1] + red2[2] + red2[3];
    __syncthreads();
    float inv = 1.f / red2[0];
    for (int s = tid; s < S_; s += 256) attw[b * S_ + s] *= inv;
}

// ---------------------------------------------------------------------------
// att4[z][b][h] = sum_{s in z-chunk} bf16(mm[b,s,h]) * attw[b,s]   (4 s-chunks)
__global__ __launch_bounds__(256)
void attended4(const unsigned short* __restrict__ mm, const float* __restrict__ attw,
               float* __restrict__ att4) {
    int b = blockIdx.x;
    int h = blockIdx.y * 256 + threadIdx.x;
    int z = blockIdx.z;
    __shared__ float w[128];
    int s0 = z * 128;
    if (threadIdx.x < 128) w[threadIdx.x] = attw[b * S_ + s0 + threadIdx.x];
    __syncthreads();
    float acc = 0.f;
    for (int s = 0; s < 128; ++s)
        acc += __uint_as_float((unsigned int)mm[((size_t)b * S_ + s0 + s) * HID_ + h] << 16) * w[s];
    att4[((size_t)z * B_ + b) * HID_ + h] = acc;
}

// ---------------------------------------------------------------------------
__global__ __launch_bounds__(256)
void hist_avg(const float* __restrict__ ph, const int* __restrict__ hcnt,
              float* __restrict__ havg) {
    int bk = blockIdx.x;
    int cnt = hcnt[bk];
    float denom = (float)(cnt > 1 ? cnt : 1);
    const float* base = ph + (size_t)bk * HL_ * EMB_;
    for (int e = threadIdx.x; e < EMB_; e += 256) {
        float s = 0.f;
        for (int l = 0; l < cnt; ++l) s += base[l * EMB_ + e];
        havg[bk * EMB_ + e] = s / denom;
    }
}

// ---------------------------------------------------------------------------
// combine_all: reduce split-K partials of hproj(8) and sep0(16), add biases,
// relu/merge per reference, L2-normalize, dot with attended (sum of 4 chunks).
__global__ __launch_bounds__(256)
void combine_all(const float* __restrict__ skA, const float* __restrict__ skB,
                 const float* __restrict__ b_hist, const float* __restrict__ b_sep,
                 const int* __restrict__ hcnt, const float* __restrict__ att4,
                 float* __restrict__ out) {
    const int MNA = B_ * K_ * HID_;
    int bk = blockIdx.x, tid = threadIdx.x;
    int b = bk / K_;
    int cnt = hcnt[bk];
    float sq = 0.f, dt = 0.f;
    #pragma unroll
    for (int i = 0; i < HID_ / 256; ++i) {
        int h = tid + i * 256;
        size_t idx = (size_t)bk * HID_ + h;
        float hp = b_hist[h];
        #pragma unroll
        for (int z = 0; z < 8; ++z) hp += skA[(size_t)z * MNA + idx];
        hp = fmaxf(hp, 0.f);
        float sp = b_sep[h];
        #pragma unroll
        for (int z = 0; z < 16; ++z) sp += skB[(size_t)z * MNA + idx];
        float v = sp + (cnt > 0 ? hp : 0.f);
        v = fmaxf(v, 0.f);
        float at = 0.f;
        #pragma unroll
        for (int z = 0; z < 4; ++z) at += att4[((size_t)z * B_ + b) * HID_ + h];
        sq += v * v;
        dt += v * at;
    }
    #pragma unroll
    for (int off = 32; off; off >>= 1) {
        sq += __shfl_down(sq, off, 64);
        dt += __shfl_down(dt, off, 64);
    }
    __shared__ float rs[4], rd[4];
    int lane = tid & 63, wv = tid >> 6;
    if (lane == 0) { rs[wv] = sq; rd[wv] = dt; }
    __syncthreads();
    if (tid == 0) {
        float Sq = rs[0] + rs[1] + rs[2] + rs[3];
        float Dt = rd[0] + rd[1] + rd[2] + rd[3];
        float norm = fmaxf(sqrtf(Sq), 1e-12f);
        out[bk] = Dt / norm;
    }
}

// ---------------------------------------------------------------------------
extern "C" void kernel_launch(void* const* d_in, const int* in_sizes, int n_in,
                              void* d_out, int out_size, void* d_ws, size_t ws_size,
                              hipStream_t stream) {
    const float* reps     = (const float*)d_in[0];
    const float* sep_imgs = (const float*)d_in[2];
    const float* vctx     = (const float*)d_in[3];
    const float* phist    = (const float*)d_in[4];
    const int*   hcnt     = (const int*)d_in[5];
    const void*  masks    = d_in[6];
    const float* W_sep = (const float*)d_in[7];
    const float* b_sep = (const float*)d_in[8];
    const float* W_e2h = (const float*)d_in[9];
    const float* b_e2h = (const float*)d_in[10];
    const float* W_hist = (const float*)d_in[11];
    const float* b_hist = (const float*)d_in[12];
    const float* W_ctx = (const float*)d_in[13];
    const float* b_ctx = (const float*)d_in[14];
    const float* W_mm = (const float*)d_in[15];
    const float* b_mm = (const float*)d_in[16];
    const float* W_a1 = (const float*)d_in[17];
    const float* b_a1 = (const float*)d_in[18];
    const float* W_a2 = (const float*)d_in[19];
    const float* b_a2 = (const float*)d_in[20];
    float* out = (float*)d_out;

    const size_t MS = (size_t)MS_;
    const int MNA = B_ * K_ * HID_;   // 196608

    // ---- workspace layout ----
    unsigned short* actA  = (unsigned short*)d_ws;          // [MS*HID] input_reps bf16
    unsigned short* actB  = actA + MS * HID_;               // [MS*HID] mm bf16
    unsigned short* WtE2H = actB + MS * HID_;               // [512*768]
    unsigned short* WtMM  = WtE2H + (size_t)EMB_ * HID_;    // [512*512]
    unsigned short* WtA1  = WtMM + (size_t)HID_ * HID_;     // [512*512]
    float* skC    = (float*)(WtA1 + (size_t)HID_ * HID_);   // [64 * 64*512] ctx splits
    float* skA    = skC + (size_t)64 * B_ * HID_;           // [8  * 384*512] hproj splits
    float* skB    = skA + (size_t)8 * MNA;                  // [16 * 384*512] sep0 splits
    float* scores8 = skB + (size_t)16 * MNA;                // [8 * MS]
    float* attw   = scores8 + 8 * MS;                       // [B,S]
    float* att4   = attw + MS;                              // [4,B,HID]
    float* ctx    = att4 + (size_t)4 * B_ * HID_;           // [B,HID]
    float* ctx2   = ctx + B_ * HID_;                        // [B,HID]
    float* havg   = ctx2 + B_ * HID_;                       // [B*K,EMB]
    int*   flag   = (int*)(havg + (size_t)B_ * K_ * EMB_);

    // 1. prep: weight transposes (bf16) + mask dtype probe
    prep<<<dim3(EMB_ / 32, HID_ / 32, 4), 256, 0, stream>>>(
        W_e2h, W_mm, W_a1, WtE2H, WtMM, WtA1, (const unsigned char*)masks, flag);

    // 2. ctx = relu(visual_context @ W_ctx + b_ctx)   [64,512], K=12288, split-K 64
    {
        const int nsp = 64, kps = (K_ * IMG_) / nsp;
        gemm_splitk<<<dim3(8, 1, nsp), 256, 0, stream>>>(vctx, W_ctx, skC,
                                                         B_, HID_, K_ * IMG_, kps);
        reduce_k<1><<<(B_ * HID_ + 255) / 256, 256, 0, stream>>>(skC, b_ctx, ctx,
                                                                 B_ * HID_, HID_, nsp);
    }
    // 3. ctx2 = ctx @ W_mm[H:,:] + b_mm               [64,512], K=512, split-K 8
    {
        const int nsp = 8, kps = HID_ / nsp;
        gemm_splitk<<<dim3(8, 1, nsp), 256, 0, stream>>>(ctx, W_mm + (size_t)HID_ * HID_,
                                                         skC, B_, HID_, HID_, kps);
        reduce_k<0><<<(B_ * HID_ + 255) / 256, 256, 0, stream>>>(skC, b_mm, ctx2,
                                                                 B_ * HID_, HID_, nsp);
    }

    const int big_grid = (MS_ / 128) * (HID_ / 128);   // 1024, % 8 == 0
    // 4. input_reps = relu(reps @ W_e2h + b_e2h)   fp32-in MFMA -> bf16 actA
    gemm_f32in<1><<<big_grid, 256, 0, stream>>>(reps, WtE2H, b_e2h, actA,
                                                MS_, HID_, EMB_);
    // 5. mm = relu(input_reps @ W_mm[:H] + ctx2[b]) -> bf16 actB
    gemm_bf16<1><<<big_grid, 256, 0, stream>>>(actA, WtMM, nullptr, ctx2, S_,
                                               actB, MS_, HID_, HID_);
    // 6. fused t=tanh(mm@W_a1+b_a1); scores8 = partial dots with W_a2
    gemm_score<<<big_grid, 256, 0, stream>>>(actB, WtA1, b_a1, W_a2, scores8,
                                             MS_, ATT_, HID_);
    // 7. masked softmax (sums 8 slots + b_a2) -> attw
    softmax8<<<B_, 256, 0, stream>>>(scores8, b_a2, masks, flag, attw);
    // 8. attended partials over 4 s-chunks
    attended4<<<dim3(B_, HID_ / 256, 4), 256, 0, stream>>>(actB, attw, att4);
    // 9. havg
    hist_avg<<<B_ * K_, 256, 0, stream>>>(phist, hcnt, havg);
    // 10. hproj partials                              [384,512], K=768, split-K 8
    gemm_splitk<<<dim3(8, 6, 8), 256, 0, stream>>>(havg, W_hist, skA,
                                                   B_ * K_, HID_, EMB_, EMB_ / 8);
    // 11. sep0 partials                               [384,512], K=2048, split-K 16
    gemm_splitk<<<dim3(8, 6, 16), 256, 0, stream>>>(sep_imgs, W_sep, skB,
                                                    B_ * K_, HID_, IMG_, IMG_ / 16);
    // 12. combine: reduce partials, relu/merge, L2-normalize, dot -> out [384]
    combine_all<<<B_ * K_, 256, 0, stream>>>(skA, skB, b_hist, b_sep, hcnt,
                                             att4, out);
}